// Round 5
// baseline (7333.480 us; speedup 1.0000x reference)
//
#include <hip/hip_runtime.h>
#include <math.h>

constexpr int DIM = 2048, EMB = 512, HID = 512, VOC = 32000, TLEN = 32, G3 = 1536;
constexpr int NB = 256;     // blocks; 1 block/CU co-resident (grid <= 256 CUs) -- PROVEN topology
constexpr int NT = 512;     // threads/block (8 waves = 2 waves/SIMD)
constexpr int ROWS = 125;   // vocab rows per block
constexpr unsigned MAGIC = 0x13579BDFu;

// ---- workspace layout (float units) ----
constexpr size_t W_H1  = 0;                          // [8][2048]
constexpr size_t W_H2  = W_H1 + 8 * 2048;            // [8][2048]
constexpr size_t W_IMG = W_H2 + 8 * 2048;            // [8][512]
constexpr size_t W_GI  = W_IMG + 8 * 512;            // [8][1536] giU (unnormalized)
constexpr size_t W_GH  = W_GI + 8 * 1536;            // [8][1536] gh (with bias)
constexpr size_t W_SB  = W_GH + 8 * 1536;            // [32][4096] per-step e accumulators
constexpr size_t W_RS  = W_SB + (size_t)TLEN * 4096; // [32][8] per-step rowsum accumulators
constexpr size_t W_AF  = W_RS + TLEN * 8;            // 256 slots x 16 uints (encoder arrive)
constexpr size_t W_GF  = W_AF + 256 * 16;            // 64 slots (gi done)
constexpr size_t W_HF  = W_GF + 64 * 16;             // 64 slots (gh done)
constexpr size_t W_CNT = W_HF + 64 * 16;             // cnt_gru @0, cnt_e @16 (32 uints)
constexpr size_t W_RDY = W_CNT + 32;                 // 1 slot (init handshake)
constexpr int FLAG_WORDS = 256 * 16 + 64 * 16 * 2 + 32;  // zeroed region (excl. ready)

__device__ __forceinline__ float dot4(float4 a, float4 b) {
  return a.x * b.x + a.y * b.y + a.z * b.z + a.w * b.w;
}
__device__ __forceinline__ float4 fma4(float4 acc, float s, float4 v) {
  acc.x += s * v.x; acc.y += s * v.y; acc.z += s * v.z; acc.w += s * v.w; return acc;
}
__device__ __forceinline__ float4 add4(float4 a, float4 b) {
  a.x += b.x; a.y += b.y; a.z += b.z; a.w += b.w; return a;
}
__device__ __forceinline__ float sigm(float x) { return 1.0f / (1.0f + __expf(-x)); }
__device__ __forceinline__ float selLane8(const float pb[8]) {
  int lane = threadIdx.x & 63;
  float r = 0.0f;
#pragma unroll
  for (int b = 0; b < 8; b++) r = (lane == b) ? pb[b] : r;
  return r;
}

// ---- coherent (cache-bypassing) accessors for step-varying cross-block data ----
__device__ __forceinline__ void stC(float* p, float v) {
  __hip_atomic_store(p, v, __ATOMIC_RELAXED, __HIP_MEMORY_SCOPE_AGENT);
}
__device__ __forceinline__ float ldC(const float* p) {
  return __hip_atomic_load(p, __ATOMIC_RELAXED, __HIP_MEMORY_SCOPE_AGENT);
}
__device__ __forceinline__ void vdrain() {
  asm volatile("s_waitcnt vmcnt(0)" ::: "memory");
}

template <int KLEN>
__device__ __forceinline__ void rowdot8(const float* __restrict__ wrow,
                                        const float* __restrict__ xsrc, float pb[8]) {
  constexpr int PER = KLEN / 64;
  constexpr int NF4 = PER / 4;
  int lane = threadIdx.x & 63;
  int k0 = lane * PER;
  const float4* w4 = (const float4*)(wrow + k0);
  float4 wv[NF4];
#pragma unroll
  for (int i = 0; i < NF4; i++) wv[i] = w4[i];
#pragma unroll
  for (int b = 0; b < 8; b++) {
    const float4* x4 = (const float4*)(xsrc + b * KLEN + k0);
    float s = 0.0f;
#pragma unroll
    for (int i = 0; i < NF4; i++) s += dot4(x4[i], wv[i]);
    pb[b] = s;
  }
#pragma unroll
  for (int m = 1; m < 64; m <<= 1) {
#pragma unroll
    for (int b = 0; b < 8; b++) pb[b] += __shfl_xor(pb[b], m, 64);
  }
}

// ---- fenced protocol (init / encoder phases only) ----
__device__ __forceinline__ void postSlotF(unsigned* slot, unsigned val) {
  __syncthreads();
  if (threadIdx.x == 0) {
    __threadfence();
    __hip_atomic_store(slot, val, __ATOMIC_RELEASE, __HIP_MEMORY_SCOPE_AGENT);
  }
}
__device__ __forceinline__ void pollSlotsF(const unsigned* slots, int n, unsigned tgt) {
  int tid = threadIdx.x;
  if (tid < n) {
    const unsigned* p = slots + (size_t)tid * 16;
    while (__hip_atomic_load(p, __ATOMIC_RELAXED, __HIP_MEMORY_SCOPE_AGENT) < tgt)
      __builtin_amdgcn_s_sleep(1);
  }
  __syncthreads();
  __threadfence();
}

// ---- fence-free steady-state: coherent data + drained release ----
__device__ __forceinline__ void postSlotQ(unsigned* slot, unsigned val) {
  vdrain();
  __syncthreads();
  if (threadIdx.x == 0)
    __hip_atomic_store(slot, val, __ATOMIC_RELAXED, __HIP_MEMORY_SCOPE_AGENT);
}
__device__ __forceinline__ void pollOne(const unsigned* p, unsigned tgt) {
  if (threadIdx.x == 0) {
    while (__hip_atomic_load(p, __ATOMIC_RELAXED, __HIP_MEMORY_SCOPE_AGENT) < tgt)
      __builtin_amdgcn_s_sleep(1);
  }
  __syncthreads();
}

// one vocab row: logits dot + butterfly + gumbel/exp + p store + e-accum
__device__ __forceinline__ void vocabRow(int r, float4 a0, float4 a1, float4 i0, float4 i1,
                                         const float4 hf[8][2], float4 ea[8][2],
                                         float sums[8], float* __restrict__ p_lds,
                                         const float* __restrict__ gum_lds) {
  int lane = threadIdx.x & 63;
  float pb[8];
#pragma unroll
  for (int b = 0; b < 8; b++) pb[b] = dot4(hf[b][0], a0) + dot4(hf[b][1], a1);
#pragma unroll
  for (int m = 1; m < 64; m <<= 1) {
#pragma unroll
    for (int b = 0; b < 8; b++) pb[b] += __shfl_xor(pb[b], m, 64);
  }
#pragma unroll
  for (int b = 0; b < 8; b++) {
    pb[b] = __expf(pb[b] + gum_lds[r * 8 + b]);
    sums[b] += pb[b];
  }
  if (lane == 0) {
    *(float4*)&p_lds[r * 8] = make_float4(pb[0], pb[1], pb[2], pb[3]);
    *(float4*)&p_lds[r * 8 + 4] = make_float4(pb[4], pb[5], pb[6], pb[7]);
  }
#pragma unroll
  for (int b = 0; b < 8; b++) {
    ea[b][0] = fma4(ea[b][0], pb[b], i0);
    ea[b][1] = fma4(ea[b][1], pb[b], i1);
  }
}

__global__ void __launch_bounds__(NT, 2)   // min 2 waves/EU -> VGPR cap 256 (no 128 squeeze)
InformedRnnSenderFixedLengthGS_48704929136907_kernel(
    const float* __restrict__ x, const float* __restrict__ enc_w,
    const float* __restrict__ enc_b, const float* __restrict__ out_w,
    const float* __restrict__ out_b, const float* __restrict__ emb_out,
    const float* __restrict__ emb_in, const float* __restrict__ ph,
    const float* __restrict__ w_ih, const float* __restrict__ b_ih,
    const float* __restrict__ w_hh, const float* __restrict__ b_hh,
    const float* __restrict__ gum, float* __restrict__ out, float* __restrict__ ws) {
  const int tid = threadIdx.x, blk = blockIdx.x;
  const int lane = tid & 63, wave = tid >> 6;   // wave in [0,8)

  float* h1 = ws + W_H1;
  float* h2 = ws + W_H2;
  float* img = ws + W_IMG;
  float* giU = ws + W_GI;
  float* gh = ws + W_GH;
  float* sbufU = ws + W_SB;
  float* rs_acc = ws + W_RS;
  unsigned* aflag = (unsigned*)(ws + W_AF);
  unsigned* gflag = (unsigned*)(ws + W_GF);
  unsigned* hflag = (unsigned*)(ws + W_HF);
  unsigned* cnt_gru = (unsigned*)(ws + W_CNT);
  unsigned* cnt_e = (unsigned*)(ws + W_CNT) + 16;
  unsigned* ready = (unsigned*)(ws + W_RDY);

  __shared__ float h_lds[4096];      // [8][512] hidden state
  __shared__ float red_e[4096];      // e reduce tree, waves 0-3
  __shared__ float red_e2[4096];     // e reduce tree, waves 4-7
  __shared__ float p_lds[ROWS * 8];
  __shared__ float gum_lds[ROWS * 8];
  __shared__ float bih_lds[G3];
  __shared__ float red_rs[64];
  __shared__ float inv_lds[8];

  // ---- init handshake: block 0 zeroes flags, then releases MAGIC ----
  if (blk == 0) {
    for (int i = tid; i < FLAG_WORDS; i += NT) aflag[i] = 0u;
    __syncthreads();
    if (tid == 0) {
      __threadfence();
      __hip_atomic_store(ready, MAGIC, __ATOMIC_RELEASE, __HIP_MEMORY_SCOPE_AGENT);
    }
  }
  if (tid == 0) {
    while (__hip_atomic_load(ready, __ATOMIC_ACQUIRE, __HIP_MEMORY_SCOPE_AGENT) != MAGIC)
      __builtin_amdgcn_s_sleep(1);
  }
  __syncthreads();
  __threadfence();

  // ---- E1: h1 = tanh(x @ enc_w0^T + b0); one row per wave ----
  {
    int o = blk * 8 + wave;
    float pb[8];
    rowdot8<2048>(enc_w + (size_t)o * DIM, x, pb);
    float eb = enc_b[o];
#pragma unroll
    for (int b = 0; b < 8; b++) pb[b] = tanhf(pb[b] + eb);
    float myv = selLane8(pb);
    if (lane < 8) h1[lane * DIM + o] = myv;
  }
  postSlotF(&aflag[blk * 16], 1u);
  pollSlotsF(aflag, 256, 1u);

  // ---- E2 ----
  {
    int o = blk * 8 + wave;
    float pb[8];
    rowdot8<2048>(enc_w + (size_t)DIM * DIM + (size_t)o * DIM, h1, pb);
    float eb = enc_b[DIM + o];
#pragma unroll
    for (int b = 0; b < 8; b++) pb[b] = tanhf(pb[b] + eb);
    float myv = selLane8(pb);
    if (lane < 8) h2[lane * DIM + o] = myv;
  }
  postSlotF(&aflag[blk * 16], 2u);
  pollSlotsF(aflag, 256, 2u);

  // ---- E3: img (blk<64), gh0 with bias (64..127), giU0=0 (128..191) ----
  if (blk < 64) {
    int o = blk * 8 + wave;
    float pb[8];
    rowdot8<2048>(out_w + (size_t)o * DIM, h2, pb);
    float ob = out_b[o];
#pragma unroll
    for (int b = 0; b < 8; b++) pb[b] += ob;
    float myv = selLane8(pb);
    if (lane < 8) img[lane * EMB + o] = myv;
  } else if (blk < 128) {
    int local = blk - 64;
    int kk = lane * 8;
    float4 p0 = *(const float4*)(ph + kk);
    float4 p1 = *(const float4*)(ph + kk + 4);
    for (int r = 0; r < 3; r++) {
      int j = local * 24 + wave * 3 + r;
      const float4* w4 = (const float4*)(w_hh + (size_t)j * HID + kk);
      float s = dot4(p0, w4[0]) + dot4(p1, w4[1]);
#pragma unroll
      for (int m = 1; m < 64; m <<= 1) s += __shfl_xor(s, m, 64);
      float val = s + b_hh[j];
      if (lane < 8) gh[lane * G3 + j] = val;
    }
  } else if (blk < 192) {
    int local = blk - 128;
    for (int r = 0; r < 3; r++) {
      int j = local * 24 + wave * 3 + r;
      if (lane < 8) giU[lane * G3 + j] = 0.0f;  // e0 == 0
    }
  }
  for (int i = tid; i < 4096; i += NT) h_lds[i] = ph[i & 511];
  for (int i = tid; i < G3; i += NT) bih_lds[i] = b_ih[i];
  if (tid < 8) inv_lds[tid] = 1.0f;  // step-0 giU is zero, inv moot
  __syncthreads();
  postSlotF(&aflag[blk * 16], 3u);
  pollSlotsF(aflag, 256, 3u);

  const int v0 = blk * ROWS;
  const int k0 = lane * 8;
  const int rbeg = (wave * ROWS) / 8, rend = ((wave + 1) * ROWS) / 8;

  for (int t = 0; t < TLEN; ++t) {
    // 0) coalesced gumbel tile load (in flight during the gate wait)
    for (int i = tid; i < ROWS * 8; i += NT) {
      int b = i / ROWS, vl = i - b * ROWS;
      gum_lds[vl * 8 + b] = gum[(size_t)t * (8 * VOC) + (size_t)b * VOC + v0 + vl];
    }
    // 1) wait for this step's gates (64+64 slot poll, no cache fence)
    if (t > 0) {
      if (tid < 64) {
        const unsigned* p = gflag + (size_t)tid * 16;
        while (__hip_atomic_load(p, __ATOMIC_RELAXED, __HIP_MEMORY_SCOPE_AGENT) < (unsigned)t)
          __builtin_amdgcn_s_sleep(1);
      } else if (tid < 128) {
        const unsigned* p = hflag + (size_t)(tid - 64) * 16;
        while (__hip_atomic_load(p, __ATOMIC_RELAXED, __HIP_MEMORY_SCOPE_AGENT) < (unsigned)t)
          __builtin_amdgcn_s_sleep(1);
      }
      __syncthreads();
    }
    // 2) GRU elementwise update, bank-conflict-free grid-stride float4 mapping
#pragma unroll
    for (int qq = 0; qq < 2; qq++) {
      int i4 = tid + NT * qq;          // float4 index in [0,1024)
      int b = i4 >> 7, k = (i4 & 127) * 4;
      float invb = inv_lds[b];
      const float* gib = giU + b * G3 + k;
      const float* ghb = gh + b * G3 + k;
      float4 iru, izu, inu, hrv, hzv, hnv;
      iru.x = ldC(gib + 0); iru.y = ldC(gib + 1); iru.z = ldC(gib + 2); iru.w = ldC(gib + 3);
      izu.x = ldC(gib + 512); izu.y = ldC(gib + 513); izu.z = ldC(gib + 514); izu.w = ldC(gib + 515);
      inu.x = ldC(gib + 1024); inu.y = ldC(gib + 1025); inu.z = ldC(gib + 1026); inu.w = ldC(gib + 1027);
      hrv.x = ldC(ghb + 0); hrv.y = ldC(ghb + 1); hrv.z = ldC(ghb + 2); hrv.w = ldC(ghb + 3);
      hzv.x = ldC(ghb + 512); hzv.y = ldC(ghb + 513); hzv.z = ldC(ghb + 514); hzv.w = ldC(ghb + 515);
      hnv.x = ldC(ghb + 1024); hnv.y = ldC(ghb + 1025); hnv.z = ldC(ghb + 1026); hnv.w = ldC(ghb + 1027);
      float4 br = *(const float4*)&bih_lds[k];
      float4 bz = *(const float4*)&bih_lds[512 + k];
      float4 bn = *(const float4*)&bih_lds[1024 + k];
      float4 hp = *(const float4*)&h_lds[b * 512 + k];
      float4 hv;
      {
        float r0 = sigm(invb * iru.x + br.x + hrv.x), z0 = sigm(invb * izu.x + bz.x + hzv.x);
        float n0 = tanhf(invb * inu.x + bn.x + r0 * hnv.x);
        hv.x = (1.0f - z0) * n0 + z0 * hp.x;
        r0 = sigm(invb * iru.y + br.y + hrv.y); z0 = sigm(invb * izu.y + bz.y + hzv.y);
        n0 = tanhf(invb * inu.y + bn.y + r0 * hnv.y);
        hv.y = (1.0f - z0) * n0 + z0 * hp.y;
        r0 = sigm(invb * iru.z + br.z + hrv.z); z0 = sigm(invb * izu.z + bz.z + hzv.z);
        n0 = tanhf(invb * inu.z + bn.z + r0 * hnv.z);
        hv.z = (1.0f - z0) * n0 + z0 * hp.z;
        r0 = sigm(invb * iru.w + br.w + hrv.w); z0 = sigm(invb * izu.w + bz.w + hzv.w);
        n0 = tanhf(invb * inu.w + bn.w + r0 * hnv.w);
        hv.w = (1.0f - z0) * n0 + z0 * hp.w;
      }
      *(float4*)&h_lds[b * 512 + k] = hv;
    }
    __syncthreads();
    if (tid == 0)
      __hip_atomic_fetch_add(cnt_gru, 1u, __ATOMIC_RELAXED, __HIP_MEMORY_SCOPE_AGENT);
    // 3) per-lane h fragments
    float4 hf[8][2];
#pragma unroll
    for (int b = 0; b < 8; b++) {
      hf[b][0] = *(const float4*)(h_lds + b * 512 + k0);
      hf[b][1] = *(const float4*)(h_lds + b * 512 + k0 + 4);
    }
    // 4) vocab rows, batched by 8 with hoisted loads (15-16 rows per wave)
    float4 ea[8][2];
#pragma unroll
    for (int b = 0; b < 8; b++) { ea[b][0] = make_float4(0, 0, 0, 0); ea[b][1] = make_float4(0, 0, 0, 0); }
    float sums[8] = {0, 0, 0, 0, 0, 0, 0, 0};
    int r = rbeg;
    for (; r + 8 <= rend; r += 8) {
      float4 A0[8], A1[8], I0[8], I1[8];
#pragma unroll
      for (int u = 0; u < 8; u++) {
        int v = v0 + r + u;
        const float4* wo = (const float4*)(emb_out + (size_t)v * EMB + k0);
        A0[u] = wo[0]; A1[u] = wo[1];
        const float4* wi = (const float4*)(emb_in + (size_t)v * EMB + k0);
        I0[u] = wi[0]; I1[u] = wi[1];
      }
#pragma unroll
      for (int u = 0; u < 8; u++)
        vocabRow(r + u, A0[u], A1[u], I0[u], I1[u], hf, ea, sums, p_lds, gum_lds);
    }
    {
      int rem = rend - r;
      if (rem > 0) {
        float4 A0[8], A1[8], I0[8], I1[8];
#pragma unroll
        for (int u = 0; u < 8; u++) {
          int rr = (u < rem) ? (r + u) : r;
          int v = v0 + rr;
          const float4* wo = (const float4*)(emb_out + (size_t)v * EMB + k0);
          A0[u] = wo[0]; A1[u] = wo[1];
          const float4* wi = (const float4*)(emb_in + (size_t)v * EMB + k0);
          I0[u] = wi[0]; I1[u] = wi[1];
        }
#pragma unroll
        for (int u = 0; u < 8; u++)
          if (u < rem)
            vocabRow(r + u, A0[u], A1[u], I0[u], I1[u], hf, ea, sums, p_lds, gum_lds);
      }
    }
    // 5) cross-wave e reduce: two parallel 4-round trees; combine folded into atomics
    for (int w = 0; w < 4; w++) {
      if (wave == w) {
#pragma unroll
        for (int b = 0; b < 8; b++) {
          float4* d = (float4*)&red_e[b * 512 + k0];
          if (w == 0) { d[0] = ea[b][0]; d[1] = ea[b][1]; }
          else { d[0] = add4(d[0], ea[b][0]); d[1] = add4(d[1], ea[b][1]); }
        }
      } else if (wave == w + 4) {
#pragma unroll
        for (int b = 0; b < 8; b++) {
          float4* d = (float4*)&red_e2[b * 512 + k0];
          if (w == 0) { d[0] = ea[b][0]; d[1] = ea[b][1]; }
          else { d[0] = add4(d[0], ea[b][0]); d[1] = add4(d[1], ea[b][1]); }
        }
      }
      __syncthreads();
    }
    if (lane == 0) {
      *(float4*)&red_rs[wave * 8] = make_float4(sums[0], sums[1], sums[2], sums[3]);
      *(float4*)&red_rs[wave * 8 + 4] = make_float4(sums[4], sums[5], sums[6], sums[7]);
    }
    __syncthreads();
    // 6) hardware-atomic e reduction: 8 fadds/thread into this step's slot
    {
      float* sb = sbufU + (size_t)t * 4096;
      for (int i = tid; i < 4096; i += NT) unsafeAtomicAdd(&sb[i], red_e[i] + red_e2[i]);
      if (tid < 8) {
        float tot = 0.0f;
#pragma unroll
        for (int w = 0; w < 8; w++) tot += red_rs[w * 8 + tid];
        unsafeAtomicAdd(&rs_acc[t * 8 + tid], tot);
      }
    }
    vdrain();           // atomics acked at coherence point
    __syncthreads();
    if (tid == 0)
      __hip_atomic_fetch_add(cnt_e, 1u, __ATOMIC_RELAXED, __HIP_MEMORY_SCOPE_AGENT);

    // ---- roles ----
    if (blk >= 64 && blk < 128 && t < TLEN - 1) {  // giU producers
      pollOne(cnt_e, (unsigned)(NB * (t + 1)));
      float sf[8][8];
#pragma unroll
      for (int b = 0; b < 8; b++)
#pragma unroll
        for (int q = 0; q < 8; q++)
          sf[b][q] = ldC(sbufU + (size_t)t * 4096 + b * 512 + k0 + q) * img[b * 512 + k0 + q];
      int local = blk - 64;
      for (int r2 = 0; r2 < 3; r2++) {
        int j = local * 24 + wave * 3 + r2;
        const float* wr = w_ih + (size_t)j * HID + k0;
        float4 w0 = *(const float4*)wr, w1 = *(const float4*)(wr + 4);
        float wv[8] = {w0.x, w0.y, w0.z, w0.w, w1.x, w1.y, w1.z, w1.w};
        float pb[8];
#pragma unroll
        for (int b = 0; b < 8; b++) {
          float s = 0.0f;
#pragma unroll
          for (int q = 0; q < 8; q++) s += sf[b][q] * wv[q];
          pb[b] = s;
        }
#pragma unroll
        for (int m = 1; m < 64; m <<= 1) {
#pragma unroll
          for (int b = 0; b < 8; b++) pb[b] += __shfl_xor(pb[b], m, 64);
        }
        float myv = selLane8(pb);
        if (lane < 8) stC(&giU[lane * G3 + j], myv);
      }
      postSlotQ(&gflag[local * 16], (unsigned)(t + 1));
    }
    if (blk >= 128 && blk < 192 && t < TLEN - 1) {  // gh producers (with bias)
      pollOne(cnt_gru, (unsigned)(NB * (t + 1)));   // WAR: all blocks done reading gh(t)
      int local = blk - 128;
      for (int r2 = 0; r2 < 3; r2++) {
        int j = local * 24 + wave * 3 + r2;
        const float4* w4 = (const float4*)(w_hh + (size_t)j * HID + k0);
        float4 w0 = w4[0], w1 = w4[1];
        float pb[8];
#pragma unroll
        for (int b = 0; b < 8; b++) pb[b] = dot4(hf[b][0], w0) + dot4(hf[b][1], w1);
#pragma unroll
        for (int m = 1; m < 64; m <<= 1) {
#pragma unroll
          for (int b = 0; b < 8; b++) pb[b] += __shfl_xor(pb[b], m, 64);
        }
        float bh = b_hh[j];
#pragma unroll
        for (int b = 0; b < 8; b++) pb[b] += bh;
        float myv = selLane8(pb);
        if (lane < 8) stC(&gh[lane * G3 + j], myv);
      }
      postSlotQ(&hflag[local * 16], (unsigned)(t + 1));
    }
    // ---- x_t normalize + write (all blocks); latches inv for next GRU ----
    pollOne(cnt_e, (unsigned)(NB * (t + 1)));
    if (tid < 8) inv_lds[tid] = 1.0f / ldC(&rs_acc[t * 8 + tid]);
    __syncthreads();
    for (int i = tid; i < ROWS * 8; i += NT) {
      int b = i / ROWS, vl = i - b * ROWS;
      out[(size_t)b * ((size_t)TLEN * VOC) + (size_t)t * VOC + v0 + vl] =
          p_lds[vl * 8 + b] * inv_lds[b];
    }
  }
}

extern "C" void kernel_launch(void* const* d_in, const int* in_sizes, int n_in,
                              void* d_out, int out_size, void* d_ws, size_t ws_size,
                              hipStream_t stream) {
  const float* x = (const float*)d_in[0];
  const float* enc_w = (const float*)d_in[1];
  const float* enc_b = (const float*)d_in[2];
  const float* out_w = (const float*)d_in[3];
  const float* out_b = (const float*)d_in[4];
  const float* emb_out = (const float*)d_in[5];
  const float* emb_in = (const float*)d_in[6];
  const float* ph = (const float*)d_in[7];
  const float* w_ih = (const float*)d_in[8];
  const float* b_ih = (const float*)d_in[9];
  const float* w_hh = (const float*)d_in[10];
  const float* b_hh = (const float*)d_in[11];
  const float* gum = (const float*)d_in[12];
  float* out = (float*)d_out;
  float* ws = (float*)d_ws;

  InformedRnnSenderFixedLengthGS_48704929136907_kernel<<<dim3(NB), dim3(NT), 0, stream>>>(
      x, enc_w, enc_b, out_w, out_b, emb_out, emb_in, ph, w_ih, b_ih, w_hh, b_hh, gum,
      out, ws);
}

// Round 6
// 7261.840 us; speedup vs baseline: 1.0099x; 1.0099x over previous
//
#include <hip/hip_runtime.h>
#include <math.h>

constexpr int DIM = 2048, EMB = 512, HID = 512, VOC = 32000, TLEN = 32, G3 = 1536;
constexpr int NB = 256;     // blocks; 1 block/CU co-resident (grid <= 256 CUs) -- PROVEN topology
constexpr int NT = 512;     // threads/block (8 waves = 2 waves/SIMD)
constexpr int ROWS = 125;   // vocab rows per block
constexpr unsigned MAGIC = 0x13579BDFu;

// ---- workspace layout (float units) ----
constexpr size_t W_H1  = 0;                          // [8][2048]
constexpr size_t W_H2  = W_H1 + 8 * 2048;            // [8][2048]
constexpr size_t W_IMG = W_H2 + 8 * 2048;            // [8][512]
constexpr size_t W_GI  = W_IMG + 8 * 512;            // [8][1536] giU (unnormalized)
constexpr size_t W_GH  = W_GI + 8 * 1536;            // [8][1536] gh (with bias)
constexpr size_t W_SB  = W_GH + 8 * 1536;            // [32][4096] per-step e accumulators
constexpr size_t W_RS  = W_SB + (size_t)TLEN * 4096; // [32][8] per-step rowsum accumulators
constexpr size_t W_AF  = W_RS + TLEN * 8;            // 256 slots x 16 uints (encoder arrive)
constexpr size_t W_GF  = W_AF + 256 * 16;            // 64 slots (gi done)
constexpr size_t W_HF  = W_GF + 64 * 16;             // 64 slots (gh done)
constexpr size_t W_CNT = W_HF + 64 * 16;             // cnt_gru @0, cnt_e @16 (32 uints)
constexpr size_t W_RDY = W_CNT + 32;                 // 1 slot (init handshake)
constexpr int FLAG_WORDS = 256 * 16 + 64 * 16 * 2 + 32;  // zeroed region (excl. ready)

__device__ __forceinline__ float dot4(float4 a, float4 b) {
  return a.x * b.x + a.y * b.y + a.z * b.z + a.w * b.w;
}
__device__ __forceinline__ float4 fma4(float4 acc, float s, float4 v) {
  acc.x += s * v.x; acc.y += s * v.y; acc.z += s * v.z; acc.w += s * v.w; return acc;
}
__device__ __forceinline__ float4 add4(float4 a, float4 b) {
  a.x += b.x; a.y += b.y; a.z += b.z; a.w += b.w; return a;
}
__device__ __forceinline__ float sigm(float x) { return 1.0f / (1.0f + __expf(-x)); }
__device__ __forceinline__ float selLane8(const float pb[8]) {
  int lane = threadIdx.x & 63;
  float r = 0.0f;
#pragma unroll
  for (int b = 0; b < 8; b++) r = (lane == b) ? pb[b] : r;
  return r;
}

// ---- coherent (cache-bypassing) accessors for step-varying cross-block data ----
__device__ __forceinline__ void stC(float* p, float v) {
  __hip_atomic_store(p, v, __ATOMIC_RELAXED, __HIP_MEMORY_SCOPE_AGENT);
}
__device__ __forceinline__ float ldC(const float* p) {
  return __hip_atomic_load(p, __ATOMIC_RELAXED, __HIP_MEMORY_SCOPE_AGENT);
}
__device__ __forceinline__ void vdrain() {
  asm volatile("s_waitcnt vmcnt(0)" ::: "memory");
}

template <int KLEN>
__device__ __forceinline__ void rowdot8(const float* __restrict__ wrow,
                                        const float* __restrict__ xsrc, float pb[8]) {
  constexpr int PER = KLEN / 64;
  constexpr int NF4 = PER / 4;
  int lane = threadIdx.x & 63;
  int k0 = lane * PER;
  const float4* w4 = (const float4*)(wrow + k0);
  float4 wv[NF4];
#pragma unroll
  for (int i = 0; i < NF4; i++) wv[i] = w4[i];
#pragma unroll
  for (int b = 0; b < 8; b++) {
    const float4* x4 = (const float4*)(xsrc + b * KLEN + k0);
    float s = 0.0f;
#pragma unroll
    for (int i = 0; i < NF4; i++) s += dot4(x4[i], wv[i]);
    pb[b] = s;
  }
#pragma unroll
  for (int m = 1; m < 64; m <<= 1) {
#pragma unroll
    for (int b = 0; b < 8; b++) pb[b] += __shfl_xor(pb[b], m, 64);
  }
}

// ---- fenced protocol (init / encoder phases only) ----
__device__ __forceinline__ void postSlotF(unsigned* slot, unsigned val) {
  __syncthreads();
  if (threadIdx.x == 0) {
    __threadfence();
    __hip_atomic_store(slot, val, __ATOMIC_RELEASE, __HIP_MEMORY_SCOPE_AGENT);
  }
}
__device__ __forceinline__ void pollSlotsF(const unsigned* slots, int n, unsigned tgt) {
  int tid = threadIdx.x;
  if (tid < n) {
    const unsigned* p = slots + (size_t)tid * 16;
    while (__hip_atomic_load(p, __ATOMIC_RELAXED, __HIP_MEMORY_SCOPE_AGENT) < tgt)
      __builtin_amdgcn_s_sleep(1);
  }
  __syncthreads();
  __threadfence();
}

// ---- fence-free steady-state: coherent data + drained release ----
__device__ __forceinline__ void postSlotQ(unsigned* slot, unsigned val) {
  vdrain();
  __syncthreads();
  if (threadIdx.x == 0)
    __hip_atomic_store(slot, val, __ATOMIC_RELAXED, __HIP_MEMORY_SCOPE_AGENT);
}
__device__ __forceinline__ void pollOne(const unsigned* p, unsigned tgt) {
  if (threadIdx.x == 0) {
    while (__hip_atomic_load(p, __ATOMIC_RELAXED, __HIP_MEMORY_SCOPE_AGENT) < tgt)
      __builtin_amdgcn_s_sleep(1);
  }
  __syncthreads();
}

// one vocab row: logits dot + butterfly + gumbel/exp + p store + e-accum
__device__ __forceinline__ void vocabRow(int r, float4 a0, float4 a1, float4 i0, float4 i1,
                                         const float4 hf[8][2], float4 ea[8][2],
                                         float sums[8], float* __restrict__ p_lds,
                                         const float* __restrict__ gum_lds) {
  int lane = threadIdx.x & 63;
  float pb[8];
#pragma unroll
  for (int b = 0; b < 8; b++) pb[b] = dot4(hf[b][0], a0) + dot4(hf[b][1], a1);
#pragma unroll
  for (int m = 1; m < 64; m <<= 1) {
#pragma unroll
    for (int b = 0; b < 8; b++) pb[b] += __shfl_xor(pb[b], m, 64);
  }
#pragma unroll
  for (int b = 0; b < 8; b++) {
    pb[b] = __expf(pb[b] + gum_lds[r * 8 + b]);
    sums[b] += pb[b];
  }
  if (lane == 0) {
    *(float4*)&p_lds[r * 8] = make_float4(pb[0], pb[1], pb[2], pb[3]);
    *(float4*)&p_lds[r * 8 + 4] = make_float4(pb[4], pb[5], pb[6], pb[7]);
  }
#pragma unroll
  for (int b = 0; b < 8; b++) {
    ea[b][0] = fma4(ea[b][0], pb[b], i0);
    ea[b][1] = fma4(ea[b][1], pb[b], i1);
  }
}

// amdgpu_waves_per_eu(2,2): pin min AND max waves/EU -> VGPR budget fixed at 256/wave.
// (__launch_bounds__ alone sets only the min; the backend then targeted 4 waves/EU
//  from the LDS estimate and squeezed VGPRs to 128 -> spill storm, rounds 1 & 5.)
__global__ void __launch_bounds__(NT)
__attribute__((amdgpu_waves_per_eu(2, 2)))
InformedRnnSenderFixedLengthGS_48704929136907_kernel(
    const float* __restrict__ x, const float* __restrict__ enc_w,
    const float* __restrict__ enc_b, const float* __restrict__ out_w,
    const float* __restrict__ out_b, const float* __restrict__ emb_out,
    const float* __restrict__ emb_in, const float* __restrict__ ph,
    const float* __restrict__ w_ih, const float* __restrict__ b_ih,
    const float* __restrict__ w_hh, const float* __restrict__ b_hh,
    const float* __restrict__ gum, float* __restrict__ out, float* __restrict__ ws) {
  const int tid = threadIdx.x, blk = blockIdx.x;
  const int lane = tid & 63, wave = tid >> 6;   // wave in [0,8)

  float* h1 = ws + W_H1;
  float* h2 = ws + W_H2;
  float* img = ws + W_IMG;
  float* giU = ws + W_GI;
  float* gh = ws + W_GH;
  float* sbufU = ws + W_SB;
  float* rs_acc = ws + W_RS;
  unsigned* aflag = (unsigned*)(ws + W_AF);
  unsigned* gflag = (unsigned*)(ws + W_GF);
  unsigned* hflag = (unsigned*)(ws + W_HF);
  unsigned* cnt_gru = (unsigned*)(ws + W_CNT);
  unsigned* cnt_e = (unsigned*)(ws + W_CNT) + 16;
  unsigned* ready = (unsigned*)(ws + W_RDY);

  __shared__ float h_lds[4096];      // [8][512] hidden state
  __shared__ float red_e[4096];      // e reduce tree, waves 0-3
  __shared__ float red_e2[4096];     // e reduce tree, waves 4-7
  __shared__ float p_lds[ROWS * 8];
  __shared__ float gum_lds[ROWS * 8];
  __shared__ float bih_lds[G3];
  __shared__ float red_rs[64];
  __shared__ float inv_lds[8];

  // ---- init handshake: block 0 zeroes flags, then releases MAGIC ----
  if (blk == 0) {
    for (int i = tid; i < FLAG_WORDS; i += NT) aflag[i] = 0u;
    __syncthreads();
    if (tid == 0) {
      __threadfence();
      __hip_atomic_store(ready, MAGIC, __ATOMIC_RELEASE, __HIP_MEMORY_SCOPE_AGENT);
    }
  }
  if (tid == 0) {
    while (__hip_atomic_load(ready, __ATOMIC_ACQUIRE, __HIP_MEMORY_SCOPE_AGENT) != MAGIC)
      __builtin_amdgcn_s_sleep(1);
  }
  __syncthreads();
  __threadfence();

  // ---- E1: h1 = tanh(x @ enc_w0^T + b0); one row per wave ----
  {
    int o = blk * 8 + wave;
    float pb[8];
    rowdot8<2048>(enc_w + (size_t)o * DIM, x, pb);
    float eb = enc_b[o];
#pragma unroll
    for (int b = 0; b < 8; b++) pb[b] = tanhf(pb[b] + eb);
    float myv = selLane8(pb);
    if (lane < 8) h1[lane * DIM + o] = myv;
  }
  postSlotF(&aflag[blk * 16], 1u);
  pollSlotsF(aflag, 256, 1u);

  // ---- E2 ----
  {
    int o = blk * 8 + wave;
    float pb[8];
    rowdot8<2048>(enc_w + (size_t)DIM * DIM + (size_t)o * DIM, h1, pb);
    float eb = enc_b[DIM + o];
#pragma unroll
    for (int b = 0; b < 8; b++) pb[b] = tanhf(pb[b] + eb);
    float myv = selLane8(pb);
    if (lane < 8) h2[lane * DIM + o] = myv;
  }
  postSlotF(&aflag[blk * 16], 2u);
  pollSlotsF(aflag, 256, 2u);

  // ---- E3: img (blk<64), gh0 with bias (64..127), giU0=0 (128..191) ----
  if (blk < 64) {
    int o = blk * 8 + wave;
    float pb[8];
    rowdot8<2048>(out_w + (size_t)o * DIM, h2, pb);
    float ob = out_b[o];
#pragma unroll
    for (int b = 0; b < 8; b++) pb[b] += ob;
    float myv = selLane8(pb);
    if (lane < 8) img[lane * EMB + o] = myv;
  } else if (blk < 128) {
    int local = blk - 64;
    int kk = lane * 8;
    float4 p0 = *(const float4*)(ph + kk);
    float4 p1 = *(const float4*)(ph + kk + 4);
    for (int r = 0; r < 3; r++) {
      int j = local * 24 + wave * 3 + r;
      const float4* w4 = (const float4*)(w_hh + (size_t)j * HID + kk);
      float s = dot4(p0, w4[0]) + dot4(p1, w4[1]);
#pragma unroll
      for (int m = 1; m < 64; m <<= 1) s += __shfl_xor(s, m, 64);
      float val = s + b_hh[j];
      if (lane < 8) gh[lane * G3 + j] = val;
    }
  } else if (blk < 192) {
    int local = blk - 128;
    for (int r = 0; r < 3; r++) {
      int j = local * 24 + wave * 3 + r;
      if (lane < 8) giU[lane * G3 + j] = 0.0f;  // e0 == 0
    }
  }
  for (int i = tid; i < 4096; i += NT) h_lds[i] = ph[i & 511];
  for (int i = tid; i < G3; i += NT) bih_lds[i] = b_ih[i];
  if (tid < 8) inv_lds[tid] = 1.0f;  // step-0 giU is zero, inv moot
  __syncthreads();
  postSlotF(&aflag[blk * 16], 3u);
  pollSlotsF(aflag, 256, 3u);

  const int v0 = blk * ROWS;
  const int k0 = lane * 8;
  const int rbeg = (wave * ROWS) / 8, rend = ((wave + 1) * ROWS) / 8;

  for (int t = 0; t < TLEN; ++t) {
    // 0) coalesced gumbel tile load (in flight during the gate wait)
    for (int i = tid; i < ROWS * 8; i += NT) {
      int b = i / ROWS, vl = i - b * ROWS;
      gum_lds[vl * 8 + b] = gum[(size_t)t * (8 * VOC) + (size_t)b * VOC + v0 + vl];
    }
    // 1) wait for this step's gates (64+64 slot poll, no cache fence)
    if (t > 0) {
      if (tid < 64) {
        const unsigned* p = gflag + (size_t)tid * 16;
        while (__hip_atomic_load(p, __ATOMIC_RELAXED, __HIP_MEMORY_SCOPE_AGENT) < (unsigned)t)
          __builtin_amdgcn_s_sleep(1);
      } else if (tid < 128) {
        const unsigned* p = hflag + (size_t)(tid - 64) * 16;
        while (__hip_atomic_load(p, __ATOMIC_RELAXED, __HIP_MEMORY_SCOPE_AGENT) < (unsigned)t)
          __builtin_amdgcn_s_sleep(1);
      }
      __syncthreads();
    }
    // 2) GRU elementwise update, bank-conflict-free grid-stride float4 mapping
#pragma unroll
    for (int qq = 0; qq < 2; qq++) {
      int i4 = tid + NT * qq;          // float4 index in [0,1024)
      int b = i4 >> 7, k = (i4 & 127) * 4;
      float invb = inv_lds[b];
      const float* gib = giU + b * G3 + k;
      const float* ghb = gh + b * G3 + k;
      float4 iru, izu, inu, hrv, hzv, hnv;
      iru.x = ldC(gib + 0); iru.y = ldC(gib + 1); iru.z = ldC(gib + 2); iru.w = ldC(gib + 3);
      izu.x = ldC(gib + 512); izu.y = ldC(gib + 513); izu.z = ldC(gib + 514); izu.w = ldC(gib + 515);
      inu.x = ldC(gib + 1024); inu.y = ldC(gib + 1025); inu.z = ldC(gib + 1026); inu.w = ldC(gib + 1027);
      hrv.x = ldC(ghb + 0); hrv.y = ldC(ghb + 1); hrv.z = ldC(ghb + 2); hrv.w = ldC(ghb + 3);
      hzv.x = ldC(ghb + 512); hzv.y = ldC(ghb + 513); hzv.z = ldC(ghb + 514); hzv.w = ldC(ghb + 515);
      hnv.x = ldC(ghb + 1024); hnv.y = ldC(ghb + 1025); hnv.z = ldC(ghb + 1026); hnv.w = ldC(ghb + 1027);
      float4 br = *(const float4*)&bih_lds[k];
      float4 bz = *(const float4*)&bih_lds[512 + k];
      float4 bn = *(const float4*)&bih_lds[1024 + k];
      float4 hp = *(const float4*)&h_lds[b * 512 + k];
      float4 hv;
      {
        float r0 = sigm(invb * iru.x + br.x + hrv.x), z0 = sigm(invb * izu.x + bz.x + hzv.x);
        float n0 = tanhf(invb * inu.x + bn.x + r0 * hnv.x);
        hv.x = (1.0f - z0) * n0 + z0 * hp.x;
        r0 = sigm(invb * iru.y + br.y + hrv.y); z0 = sigm(invb * izu.y + bz.y + hzv.y);
        n0 = tanhf(invb * inu.y + bn.y + r0 * hnv.y);
        hv.y = (1.0f - z0) * n0 + z0 * hp.y;
        r0 = sigm(invb * iru.z + br.z + hrv.z); z0 = sigm(invb * izu.z + bz.z + hzv.z);
        n0 = tanhf(invb * inu.z + bn.z + r0 * hnv.z);
        hv.z = (1.0f - z0) * n0 + z0 * hp.z;
        r0 = sigm(invb * iru.w + br.w + hrv.w); z0 = sigm(invb * izu.w + bz.w + hzv.w);
        n0 = tanhf(invb * inu.w + bn.w + r0 * hnv.w);
        hv.w = (1.0f - z0) * n0 + z0 * hp.w;
      }
      *(float4*)&h_lds[b * 512 + k] = hv;
    }
    __syncthreads();
    if (tid == 0)
      __hip_atomic_fetch_add(cnt_gru, 1u, __ATOMIC_RELAXED, __HIP_MEMORY_SCOPE_AGENT);
    // 3) per-lane h fragments
    float4 hf[8][2];
#pragma unroll
    for (int b = 0; b < 8; b++) {
      hf[b][0] = *(const float4*)(h_lds + b * 512 + k0);
      hf[b][1] = *(const float4*)(h_lds + b * 512 + k0 + 4);
    }
    // 4) vocab rows, batched by 8 with hoisted loads (15-16 rows per wave)
    float4 ea[8][2];
#pragma unroll
    for (int b = 0; b < 8; b++) { ea[b][0] = make_float4(0, 0, 0, 0); ea[b][1] = make_float4(0, 0, 0, 0); }
    float sums[8] = {0, 0, 0, 0, 0, 0, 0, 0};
    int r = rbeg;
    for (; r + 8 <= rend; r += 8) {
      float4 A0[8], A1[8], I0[8], I1[8];
#pragma unroll
      for (int u = 0; u < 8; u++) {
        int v = v0 + r + u;
        const float4* wo = (const float4*)(emb_out + (size_t)v * EMB + k0);
        A0[u] = wo[0]; A1[u] = wo[1];
        const float4* wi = (const float4*)(emb_in + (size_t)v * EMB + k0);
        I0[u] = wi[0]; I1[u] = wi[1];
      }
#pragma unroll
      for (int u = 0; u < 8; u++)
        vocabRow(r + u, A0[u], A1[u], I0[u], I1[u], hf, ea, sums, p_lds, gum_lds);
    }
    {
      int rem = rend - r;
      if (rem > 0) {
        float4 A0[8], A1[8], I0[8], I1[8];
#pragma unroll
        for (int u = 0; u < 8; u++) {
          int rr = (u < rem) ? (r + u) : r;
          int v = v0 + rr;
          const float4* wo = (const float4*)(emb_out + (size_t)v * EMB + k0);
          A0[u] = wo[0]; A1[u] = wo[1];
          const float4* wi = (const float4*)(emb_in + (size_t)v * EMB + k0);
          I0[u] = wi[0]; I1[u] = wi[1];
        }
#pragma unroll
        for (int u = 0; u < 8; u++)
          if (u < rem)
            vocabRow(r + u, A0[u], A1[u], I0[u], I1[u], hf, ea, sums, p_lds, gum_lds);
      }
    }
    // 5) cross-wave e reduce: two parallel 4-round trees; combine folded into atomics
    for (int w = 0; w < 4; w++) {
      if (wave == w) {
#pragma unroll
        for (int b = 0; b < 8; b++) {
          float4* d = (float4*)&red_e[b * 512 + k0];
          if (w == 0) { d[0] = ea[b][0]; d[1] = ea[b][1]; }
          else { d[0] = add4(d[0], ea[b][0]); d[1] = add4(d[1], ea[b][1]); }
        }
      } else if (wave == w + 4) {
#pragma unroll
        for (int b = 0; b < 8; b++) {
          float4* d = (float4*)&red_e2[b * 512 + k0];
          if (w == 0) { d[0] = ea[b][0]; d[1] = ea[b][1]; }
          else { d[0] = add4(d[0], ea[b][0]); d[1] = add4(d[1], ea[b][1]); }
        }
      }
      __syncthreads();
    }
    if (lane == 0) {
      *(float4*)&red_rs[wave * 8] = make_float4(sums[0], sums[1], sums[2], sums[3]);
      *(float4*)&red_rs[wave * 8 + 4] = make_float4(sums[4], sums[5], sums[6], sums[7]);
    }
    __syncthreads();
    // 6) hardware-atomic e reduction: 8 fadds/thread into this step's slot
    {
      float* sb = sbufU + (size_t)t * 4096;
      for (int i = tid; i < 4096; i += NT) unsafeAtomicAdd(&sb[i], red_e[i] + red_e2[i]);
      if (tid < 8) {
        float tot = 0.0f;
#pragma unroll
        for (int w = 0; w < 8; w++) tot += red_rs[w * 8 + tid];
        unsafeAtomicAdd(&rs_acc[t * 8 + tid], tot);
      }
    }
    vdrain();           // atomics acked at coherence point
    __syncthreads();
    if (tid == 0)
      __hip_atomic_fetch_add(cnt_e, 1u, __ATOMIC_RELAXED, __HIP_MEMORY_SCOPE_AGENT);

    // ---- roles ----
    if (blk >= 64 && blk < 128 && t < TLEN - 1) {  // giU producers
      pollOne(cnt_e, (unsigned)(NB * (t + 1)));
      float sf[8][8];
#pragma unroll
      for (int b = 0; b < 8; b++)
#pragma unroll
        for (int q = 0; q < 8; q++)
          sf[b][q] = ldC(sbufU + (size_t)t * 4096 + b * 512 + k0 + q) * img[b * 512 + k0 + q];
      int local = blk - 64;
      for (int r2 = 0; r2 < 3; r2++) {
        int j = local * 24 + wave * 3 + r2;
        const float* wr = w_ih + (size_t)j * HID + k0;
        float4 w0 = *(const float4*)wr, w1 = *(const float4*)(wr + 4);
        float wv[8] = {w0.x, w0.y, w0.z, w0.w, w1.x, w1.y, w1.z, w1.w};
        float pb[8];
#pragma unroll
        for (int b = 0; b < 8; b++) {
          float s = 0.0f;
#pragma unroll
          for (int q = 0; q < 8; q++) s += sf[b][q] * wv[q];
          pb[b] = s;
        }
#pragma unroll
        for (int m = 1; m < 64; m <<= 1) {
#pragma unroll
          for (int b = 0; b < 8; b++) pb[b] += __shfl_xor(pb[b], m, 64);
        }
        float myv = selLane8(pb);
        if (lane < 8) stC(&giU[lane * G3 + j], myv);
      }
      postSlotQ(&gflag[local * 16], (unsigned)(t + 1));
    }
    if (blk >= 128 && blk < 192 && t < TLEN - 1) {  // gh producers (with bias)
      pollOne(cnt_gru, (unsigned)(NB * (t + 1)));   // WAR: all blocks done reading gh(t)
      int local = blk - 128;
      for (int r2 = 0; r2 < 3; r2++) {
        int j = local * 24 + wave * 3 + r2;
        const float4* w4 = (const float4*)(w_hh + (size_t)j * HID + k0);
        float4 w0 = w4[0], w1 = w4[1];
        float pb[8];
#pragma unroll
        for (int b = 0; b < 8; b++) pb[b] = dot4(hf[b][0], w0) + dot4(hf[b][1], w1);
#pragma unroll
        for (int m = 1; m < 64; m <<= 1) {
#pragma unroll
          for (int b = 0; b < 8; b++) pb[b] += __shfl_xor(pb[b], m, 64);
        }
        float bh = b_hh[j];
#pragma unroll
        for (int b = 0; b < 8; b++) pb[b] += bh;
        float myv = selLane8(pb);
        if (lane < 8) stC(&gh[lane * G3 + j], myv);
      }
      postSlotQ(&hflag[local * 16], (unsigned)(t + 1));
    }
    // ---- x_t normalize + write (all blocks); latches inv for next GRU ----
    pollOne(cnt_e, (unsigned)(NB * (t + 1)));
    if (tid < 8) inv_lds[tid] = 1.0f / ldC(&rs_acc[t * 8 + tid]);
    __syncthreads();
    for (int i = tid; i < ROWS * 8; i += NT) {
      int b = i / ROWS, vl = i - b * ROWS;
      out[(size_t)b * ((size_t)TLEN * VOC) + (size_t)t * VOC + v0 + vl] =
          p_lds[vl * 8 + b] * inv_lds[b];
    }
  }
}

extern "C" void kernel_launch(void* const* d_in, const int* in_sizes, int n_in,
                              void* d_out, int out_size, void* d_ws, size_t ws_size,
                              hipStream_t stream) {
  const float* x = (const float*)d_in[0];
  const float* enc_w = (const float*)d_in[1];
  const float* enc_b = (const float*)d_in[2];
  const float* out_w = (const float*)d_in[3];
  const float* out_b = (const float*)d_in[4];
  const float* emb_out = (const float*)d_in[5];
  const float* emb_in = (const float*)d_in[6];
  const float* ph = (const float*)d_in[7];
  const float* w_ih = (const float*)d_in[8];
  const float* b_ih = (const float*)d_in[9];
  const float* w_hh = (const float*)d_in[10];
  const float* b_hh = (const float*)d_in[11];
  const float* gum = (const float*)d_in[12];
  float* out = (float*)d_out;
  float* ws = (float*)d_ws;

  InformedRnnSenderFixedLengthGS_48704929136907_kernel<<<dim3(NB), dim3(NT), 0, stream>>>(
      x, enc_w, enc_b, out_w, out_b, emb_out, emb_in, ph, w_ih, b_ih, w_hh, b_hh, gum,
      out, ws);
}

// Round 7
// 7241.548 us; speedup vs baseline: 1.0127x; 1.0028x over previous
//
#include <hip/hip_runtime.h>
#include <math.h>

constexpr int DIM = 2048, EMB = 512, HID = 512, VOC = 32000, TLEN = 32, G3 = 1536;
constexpr int NB = 256;     // blocks; 1 block/CU co-resident (grid <= 256 CUs) -- PROVEN topology
constexpr int NT = 512;     // threads/block (8 waves = 2 waves/SIMD)
constexpr int ROWS = 125;   // vocab rows per block
constexpr unsigned MAGIC = 0x13579BDFu;

// ---- workspace layout (float units) ----
constexpr size_t W_H1  = 0;                          // [8][2048]
constexpr size_t W_H2  = W_H1 + 8 * 2048;            // [8][2048]
constexpr size_t W_IMG = W_H2 + 8 * 2048;            // [8][512]
constexpr size_t W_GI  = W_IMG + 8 * 512;            // [8][1536] giU (unnormalized)
constexpr size_t W_GH  = W_GI + 8 * 1536;            // [8][1536] gh (with bias)
constexpr size_t W_SB  = W_GH + 8 * 1536;            // [32][4096] per-step e accumulators
constexpr size_t W_RS  = W_SB + (size_t)TLEN * 4096; // [32][8] per-step rowsum accumulators
constexpr size_t W_AF  = W_RS + TLEN * 8;            // 256 slots x 16 uints (encoder arrive)
constexpr size_t W_GF  = W_AF + 256 * 16;            // 64 slots (gi done)
constexpr size_t W_HF  = W_GF + 64 * 16;             // 64 slots (gh done)
constexpr size_t W_CNT = W_HF + 64 * 16;             // cnt_gru @0, cnt_e @16 (32 uints)
constexpr size_t W_RDY = W_CNT + 32;                 // 1 slot (init handshake)
constexpr int FLAG_WORDS = 256 * 16 + 64 * 16 * 2 + 32;  // zeroed region (excl. ready)

__device__ __forceinline__ float dot4(float4 a, float4 b) {
  return a.x * b.x + a.y * b.y + a.z * b.z + a.w * b.w;
}
__device__ __forceinline__ float4 fma4(float4 acc, float s, float4 v) {
  acc.x += s * v.x; acc.y += s * v.y; acc.z += s * v.z; acc.w += s * v.w; return acc;
}
__device__ __forceinline__ float4 add4(float4 a, float4 b) {
  a.x += b.x; a.y += b.y; a.z += b.z; a.w += b.w; return a;
}
__device__ __forceinline__ float sigm(float x) { return 1.0f / (1.0f + __expf(-x)); }
__device__ __forceinline__ float selLane8(const float pb[8]) {
  int lane = threadIdx.x & 63;
  float r = 0.0f;
#pragma unroll
  for (int b = 0; b < 8; b++) r = (lane == b) ? pb[b] : r;
  return r;
}

// ---- coherent (cache-bypassing) accessors for step-varying cross-block data ----
__device__ __forceinline__ void stC(float* p, float v) {
  __hip_atomic_store(p, v, __ATOMIC_RELAXED, __HIP_MEMORY_SCOPE_AGENT);
}
__device__ __forceinline__ float ldC(const float* p) {
  return __hip_atomic_load(p, __ATOMIC_RELAXED, __HIP_MEMORY_SCOPE_AGENT);
}
__device__ __forceinline__ void vdrain() {
  asm volatile("s_waitcnt vmcnt(0)" ::: "memory");
}

template <int KLEN>
__device__ __forceinline__ void rowdot8(const float* __restrict__ wrow,
                                        const float* __restrict__ xsrc, float pb[8]) {
  constexpr int PER = KLEN / 64;
  constexpr int NF4 = PER / 4;
  int lane = threadIdx.x & 63;
  int k0 = lane * PER;
  const float4* w4 = (const float4*)(wrow + k0);
  float4 wv[NF4];
#pragma unroll
  for (int i = 0; i < NF4; i++) wv[i] = w4[i];
#pragma unroll
  for (int b = 0; b < 8; b++) {
    const float4* x4 = (const float4*)(xsrc + b * KLEN + k0);
    float s = 0.0f;
#pragma unroll
    for (int i = 0; i < NF4; i++) s += dot4(x4[i], wv[i]);
    pb[b] = s;
  }
#pragma unroll
  for (int m = 1; m < 64; m <<= 1) {
#pragma unroll
    for (int b = 0; b < 8; b++) pb[b] += __shfl_xor(pb[b], m, 64);
  }
}

// ---- fenced protocol (init / encoder phases only) ----
__device__ __forceinline__ void postSlotF(unsigned* slot, unsigned val) {
  __syncthreads();
  if (threadIdx.x == 0) {
    __threadfence();
    __hip_atomic_store(slot, val, __ATOMIC_RELEASE, __HIP_MEMORY_SCOPE_AGENT);
  }
}
__device__ __forceinline__ void pollSlotsF(const unsigned* slots, int n, unsigned tgt) {
  int tid = threadIdx.x;
  if (tid < n) {
    const unsigned* p = slots + (size_t)tid * 16;
    while (__hip_atomic_load(p, __ATOMIC_RELAXED, __HIP_MEMORY_SCOPE_AGENT) < tgt)
      __builtin_amdgcn_s_sleep(1);
  }
  __syncthreads();
  __threadfence();
}

// ---- fence-free steady-state: coherent data + drained release ----
__device__ __forceinline__ void postSlotQ(unsigned* slot, unsigned val) {
  vdrain();
  __syncthreads();
  if (threadIdx.x == 0)
    __hip_atomic_store(slot, val, __ATOMIC_RELAXED, __HIP_MEMORY_SCOPE_AGENT);
}
__device__ __forceinline__ void pollOne(const unsigned* p, unsigned tgt) {
  if (threadIdx.x == 0) {
    while (__hip_atomic_load(p, __ATOMIC_RELAXED, __HIP_MEMORY_SCOPE_AGENT) < tgt)
      __builtin_amdgcn_s_sleep(1);
  }
  __syncthreads();
}

// one vocab row: logits dot + butterfly + gumbel/exp + p store + e-accum
__device__ __forceinline__ void vocabRow(int r, float4 a0, float4 a1, float4 i0, float4 i1,
                                         const float4 hf[8][2], float4 ea[8][2],
                                         float sums[8], float* __restrict__ p_lds,
                                         const float* __restrict__ gum_lds) {
  int lane = threadIdx.x & 63;
  float pb[8];
#pragma unroll
  for (int b = 0; b < 8; b++) pb[b] = dot4(hf[b][0], a0) + dot4(hf[b][1], a1);
#pragma unroll
  for (int m = 1; m < 64; m <<= 1) {
#pragma unroll
    for (int b = 0; b < 8; b++) pb[b] += __shfl_xor(pb[b], m, 64);
  }
#pragma unroll
  for (int b = 0; b < 8; b++) {
    pb[b] = __expf(pb[b] + gum_lds[r * 8 + b]);
    sums[b] += pb[b];
  }
  if (lane == 0) {
    *(float4*)&p_lds[r * 8] = make_float4(pb[0], pb[1], pb[2], pb[3]);
    *(float4*)&p_lds[r * 8 + 4] = make_float4(pb[4], pb[5], pb[6], pb[7]);
  }
#pragma unroll
  for (int b = 0; b < 8; b++) {
    ea[b][0] = fma4(ea[b][0], pb[b], i0);
    ea[b][1] = fma4(ea[b][1], pb[b], i1);
  }
}

// Occupancy shaping: LDS is padded past 80 KB below so only ONE 8-wave block fits
// per CU -> backend targets 2 waves/SIMD -> VGPR budget 512/2 = 256 (no spills).
// (__launch_bounds__ min and amdgpu_waves_per_eu were both ignored; the allocator
//  follows the LDS-derived occupancy bound -- rounds 1/5/6 evidence.)
__global__ void __launch_bounds__(NT)
InformedRnnSenderFixedLengthGS_48704929136907_kernel(
    const float* __restrict__ x, const float* __restrict__ enc_w,
    const float* __restrict__ enc_b, const float* __restrict__ out_w,
    const float* __restrict__ out_b, const float* __restrict__ emb_out,
    const float* __restrict__ emb_in, const float* __restrict__ ph,
    const float* __restrict__ w_ih, const float* __restrict__ b_ih,
    const float* __restrict__ w_hh, const float* __restrict__ b_hh,
    const float* __restrict__ gum, float* __restrict__ out, float* __restrict__ ws) {
  const int tid = threadIdx.x, blk = blockIdx.x;
  const int lane = tid & 63, wave = tid >> 6;   // wave in [0,8)

  float* h1 = ws + W_H1;
  float* h2 = ws + W_H2;
  float* img = ws + W_IMG;
  float* giU = ws + W_GI;
  float* gh = ws + W_GH;
  float* sbufU = ws + W_SB;
  float* rs_acc = ws + W_RS;
  unsigned* aflag = (unsigned*)(ws + W_AF);
  unsigned* gflag = (unsigned*)(ws + W_GF);
  unsigned* hflag = (unsigned*)(ws + W_HF);
  unsigned* cnt_gru = (unsigned*)(ws + W_CNT);
  unsigned* cnt_e = (unsigned*)(ws + W_CNT) + 16;
  unsigned* ready = (unsigned*)(ws + W_RDY);

  __shared__ float h_lds[4096];      // [8][512] hidden state
  __shared__ float red_e[4096];      // e reduce tree, waves 0-3
  __shared__ float red_e2[4096];     // e reduce tree, waves 4-7
  __shared__ float p_lds[ROWS * 8];
  __shared__ float gum_lds[ROWS * 8];
  __shared__ float bih_lds[G3];
  __shared__ float red_rs[64];
  __shared__ float inv_lds[8];
  __shared__ float lds_pad[6400];    // 25.6 KB pad -> total LDS ~89 KB -> 1 block/CU

  // keep the pad alive without ever touching it at runtime
  asm volatile("" ::"v"((unsigned)(size_t)lds_pad) : "memory");

  // ---- init handshake: block 0 zeroes flags, then releases MAGIC ----
  if (blk == 0) {
    for (int i = tid; i < FLAG_WORDS; i += NT) aflag[i] = 0u;
    __syncthreads();
    if (tid == 0) {
      __threadfence();
      __hip_atomic_store(ready, MAGIC, __ATOMIC_RELEASE, __HIP_MEMORY_SCOPE_AGENT);
    }
  }
  if (tid == 0) {
    while (__hip_atomic_load(ready, __ATOMIC_ACQUIRE, __HIP_MEMORY_SCOPE_AGENT) != MAGIC)
      __builtin_amdgcn_s_sleep(1);
  }
  __syncthreads();
  __threadfence();

  // ---- E1: h1 = tanh(x @ enc_w0^T + b0); one row per wave ----
  {
    int o = blk * 8 + wave;
    float pb[8];
    rowdot8<2048>(enc_w + (size_t)o * DIM, x, pb);
    float eb = enc_b[o];
#pragma unroll
    for (int b = 0; b < 8; b++) pb[b] = tanhf(pb[b] + eb);
    float myv = selLane8(pb);
    if (lane < 8) h1[lane * DIM + o] = myv;
  }
  postSlotF(&aflag[blk * 16], 1u);
  pollSlotsF(aflag, 256, 1u);

  // ---- E2 ----
  {
    int o = blk * 8 + wave;
    float pb[8];
    rowdot8<2048>(enc_w + (size_t)DIM * DIM + (size_t)o * DIM, h1, pb);
    float eb = enc_b[DIM + o];
#pragma unroll
    for (int b = 0; b < 8; b++) pb[b] = tanhf(pb[b] + eb);
    float myv = selLane8(pb);
    if (lane < 8) h2[lane * DIM + o] = myv;
  }
  postSlotF(&aflag[blk * 16], 2u);
  pollSlotsF(aflag, 256, 2u);

  // ---- E3: img (blk<64), gh0 with bias (64..127), giU0=0 (128..191) ----
  if (blk < 64) {
    int o = blk * 8 + wave;
    float pb[8];
    rowdot8<2048>(out_w + (size_t)o * DIM, h2, pb);
    float ob = out_b[o];
#pragma unroll
    for (int b = 0; b < 8; b++) pb[b] += ob;
    float myv = selLane8(pb);
    if (lane < 8) img[lane * EMB + o] = myv;
  } else if (blk < 128) {
    int local = blk - 64;
    int kk = lane * 8;
    float4 p0 = *(const float4*)(ph + kk);
    float4 p1 = *(const float4*)(ph + kk + 4);
    for (int r = 0; r < 3; r++) {
      int j = local * 24 + wave * 3 + r;
      const float4* w4 = (const float4*)(w_hh + (size_t)j * HID + kk);
      float s = dot4(p0, w4[0]) + dot4(p1, w4[1]);
#pragma unroll
      for (int m = 1; m < 64; m <<= 1) s += __shfl_xor(s, m, 64);
      float val = s + b_hh[j];
      if (lane < 8) gh[lane * G3 + j] = val;
    }
  } else if (blk < 192) {
    int local = blk - 128;
    for (int r = 0; r < 3; r++) {
      int j = local * 24 + wave * 3 + r;
      if (lane < 8) giU[lane * G3 + j] = 0.0f;  // e0 == 0
    }
  }
  for (int i = tid; i < 4096; i += NT) h_lds[i] = ph[i & 511];
  for (int i = tid; i < G3; i += NT) bih_lds[i] = b_ih[i];
  if (tid < 8) inv_lds[tid] = 1.0f;  // step-0 giU is zero, inv moot
  __syncthreads();
  postSlotF(&aflag[blk * 16], 3u);
  pollSlotsF(aflag, 256, 3u);

  const int v0 = blk * ROWS;
  const int k0 = lane * 8;
  const int rbeg = (wave * ROWS) / 8, rend = ((wave + 1) * ROWS) / 8;

  for (int t = 0; t < TLEN; ++t) {
    // 0) coalesced gumbel tile load (in flight during the gate wait)
    for (int i = tid; i < ROWS * 8; i += NT) {
      int b = i / ROWS, vl = i - b * ROWS;
      gum_lds[vl * 8 + b] = gum[(size_t)t * (8 * VOC) + (size_t)b * VOC + v0 + vl];
    }
    // 1) wait for this step's gates (64+64 slot poll, no cache fence)
    if (t > 0) {
      if (tid < 64) {
        const unsigned* p = gflag + (size_t)tid * 16;
        while (__hip_atomic_load(p, __ATOMIC_RELAXED, __HIP_MEMORY_SCOPE_AGENT) < (unsigned)t)
          __builtin_amdgcn_s_sleep(1);
      } else if (tid < 128) {
        const unsigned* p = hflag + (size_t)(tid - 64) * 16;
        while (__hip_atomic_load(p, __ATOMIC_RELAXED, __HIP_MEMORY_SCOPE_AGENT) < (unsigned)t)
          __builtin_amdgcn_s_sleep(1);
      }
      __syncthreads();
    }
    // 2) GRU elementwise update, bank-conflict-free grid-stride float4 mapping
#pragma unroll
    for (int qq = 0; qq < 2; qq++) {
      int i4 = tid + NT * qq;          // float4 index in [0,1024)
      int b = i4 >> 7, k = (i4 & 127) * 4;
      float invb = inv_lds[b];
      const float* gib = giU + b * G3 + k;
      const float* ghb = gh + b * G3 + k;
      float4 iru, izu, inu, hrv, hzv, hnv;
      iru.x = ldC(gib + 0); iru.y = ldC(gib + 1); iru.z = ldC(gib + 2); iru.w = ldC(gib + 3);
      izu.x = ldC(gib + 512); izu.y = ldC(gib + 513); izu.z = ldC(gib + 514); izu.w = ldC(gib + 515);
      inu.x = ldC(gib + 1024); inu.y = ldC(gib + 1025); inu.z = ldC(gib + 1026); inu.w = ldC(gib + 1027);
      hrv.x = ldC(ghb + 0); hrv.y = ldC(ghb + 1); hrv.z = ldC(ghb + 2); hrv.w = ldC(ghb + 3);
      hzv.x = ldC(ghb + 512); hzv.y = ldC(ghb + 513); hzv.z = ldC(ghb + 514); hzv.w = ldC(ghb + 515);
      hnv.x = ldC(ghb + 1024); hnv.y = ldC(ghb + 1025); hnv.z = ldC(ghb + 1026); hnv.w = ldC(ghb + 1027);
      float4 br = *(const float4*)&bih_lds[k];
      float4 bz = *(const float4*)&bih_lds[512 + k];
      float4 bn = *(const float4*)&bih_lds[1024 + k];
      float4 hp = *(const float4*)&h_lds[b * 512 + k];
      float4 hv;
      {
        float r0 = sigm(invb * iru.x + br.x + hrv.x), z0 = sigm(invb * izu.x + bz.x + hzv.x);
        float n0 = tanhf(invb * inu.x + bn.x + r0 * hnv.x);
        hv.x = (1.0f - z0) * n0 + z0 * hp.x;
        r0 = sigm(invb * iru.y + br.y + hrv.y); z0 = sigm(invb * izu.y + bz.y + hzv.y);
        n0 = tanhf(invb * inu.y + bn.y + r0 * hnv.y);
        hv.y = (1.0f - z0) * n0 + z0 * hp.y;
        r0 = sigm(invb * iru.z + br.z + hrv.z); z0 = sigm(invb * izu.z + bz.z + hzv.z);
        n0 = tanhf(invb * inu.z + bn.z + r0 * hnv.z);
        hv.z = (1.0f - z0) * n0 + z0 * hp.z;
        r0 = sigm(invb * iru.w + br.w + hrv.w); z0 = sigm(invb * izu.w + bz.w + hzv.w);
        n0 = tanhf(invb * inu.w + bn.w + r0 * hnv.w);
        hv.w = (1.0f - z0) * n0 + z0 * hp.w;
      }
      *(float4*)&h_lds[b * 512 + k] = hv;
    }
    __syncthreads();
    if (tid == 0)
      __hip_atomic_fetch_add(cnt_gru, 1u, __ATOMIC_RELAXED, __HIP_MEMORY_SCOPE_AGENT);
    // 3) per-lane h fragments
    float4 hf[8][2];
#pragma unroll
    for (int b = 0; b < 8; b++) {
      hf[b][0] = *(const float4*)(h_lds + b * 512 + k0);
      hf[b][1] = *(const float4*)(h_lds + b * 512 + k0 + 4);
    }
    // 4) vocab rows, batched by 8 with hoisted loads (15-16 rows per wave)
    float4 ea[8][2];
#pragma unroll
    for (int b = 0; b < 8; b++) { ea[b][0] = make_float4(0, 0, 0, 0); ea[b][1] = make_float4(0, 0, 0, 0); }
    float sums[8] = {0, 0, 0, 0, 0, 0, 0, 0};
    int r = rbeg;
    for (; r + 8 <= rend; r += 8) {
      float4 A0[8], A1[8], I0[8], I1[8];
#pragma unroll
      for (int u = 0; u < 8; u++) {
        int v = v0 + r + u;
        const float4* wo = (const float4*)(emb_out + (size_t)v * EMB + k0);
        A0[u] = wo[0]; A1[u] = wo[1];
        const float4* wi = (const float4*)(emb_in + (size_t)v * EMB + k0);
        I0[u] = wi[0]; I1[u] = wi[1];
      }
#pragma unroll
      for (int u = 0; u < 8; u++)
        vocabRow(r + u, A0[u], A1[u], I0[u], I1[u], hf, ea, sums, p_lds, gum_lds);
    }
    {
      int rem = rend - r;
      if (rem > 0) {
        float4 A0[8], A1[8], I0[8], I1[8];
#pragma unroll
        for (int u = 0; u < 8; u++) {
          int rr = (u < rem) ? (r + u) : r;
          int v = v0 + rr;
          const float4* wo = (const float4*)(emb_out + (size_t)v * EMB + k0);
          A0[u] = wo[0]; A1[u] = wo[1];
          const float4* wi = (const float4*)(emb_in + (size_t)v * EMB + k0);
          I0[u] = wi[0]; I1[u] = wi[1];
        }
#pragma unroll
        for (int u = 0; u < 8; u++)
          if (u < rem)
            vocabRow(r + u, A0[u], A1[u], I0[u], I1[u], hf, ea, sums, p_lds, gum_lds);
      }
    }
    // 5) cross-wave e reduce: two parallel 4-round trees; combine folded into atomics
    for (int w = 0; w < 4; w++) {
      if (wave == w) {
#pragma unroll
        for (int b = 0; b < 8; b++) {
          float4* d = (float4*)&red_e[b * 512 + k0];
          if (w == 0) { d[0] = ea[b][0]; d[1] = ea[b][1]; }
          else { d[0] = add4(d[0], ea[b][0]); d[1] = add4(d[1], ea[b][1]); }
        }
      } else if (wave == w + 4) {
#pragma unroll
        for (int b = 0; b < 8; b++) {
          float4* d = (float4*)&red_e2[b * 512 + k0];
          if (w == 0) { d[0] = ea[b][0]; d[1] = ea[b][1]; }
          else { d[0] = add4(d[0], ea[b][0]); d[1] = add4(d[1], ea[b][1]); }
        }
      }
      __syncthreads();
    }
    if (lane == 0) {
      *(float4*)&red_rs[wave * 8] = make_float4(sums[0], sums[1], sums[2], sums[3]);
      *(float4*)&red_rs[wave * 8 + 4] = make_float4(sums[4], sums[5], sums[6], sums[7]);
    }
    __syncthreads();
    // 6) hardware-atomic e reduction: 8 fadds/thread into this step's slot
    {
      float* sb = sbufU + (size_t)t * 4096;
      for (int i = tid; i < 4096; i += NT) unsafeAtomicAdd(&sb[i], red_e[i] + red_e2[i]);
      if (tid < 8) {
        float tot = 0.0f;
#pragma unroll
        for (int w = 0; w < 8; w++) tot += red_rs[w * 8 + tid];
        unsafeAtomicAdd(&rs_acc[t * 8 + tid], tot);
      }
    }
    vdrain();           // atomics acked at coherence point
    __syncthreads();
    if (tid == 0)
      __hip_atomic_fetch_add(cnt_e, 1u, __ATOMIC_RELAXED, __HIP_MEMORY_SCOPE_AGENT);

    // ---- roles ----
    if (blk >= 64 && blk < 128 && t < TLEN - 1) {  // giU producers
      pollOne(cnt_e, (unsigned)(NB * (t + 1)));
      float sf[8][8];
#pragma unroll
      for (int b = 0; b < 8; b++)
#pragma unroll
        for (int q = 0; q < 8; q++)
          sf[b][q] = ldC(sbufU + (size_t)t * 4096 + b * 512 + k0 + q) * img[b * 512 + k0 + q];
      int local = blk - 64;
      for (int r2 = 0; r2 < 3; r2++) {
        int j = local * 24 + wave * 3 + r2;
        const float* wr = w_ih + (size_t)j * HID + k0;
        float4 w0 = *(const float4*)wr, w1 = *(const float4*)(wr + 4);
        float wv[8] = {w0.x, w0.y, w0.z, w0.w, w1.x, w1.y, w1.z, w1.w};
        float pb[8];
#pragma unroll
        for (int b = 0; b < 8; b++) {
          float s = 0.0f;
#pragma unroll
          for (int q = 0; q < 8; q++) s += sf[b][q] * wv[q];
          pb[b] = s;
        }
#pragma unroll
        for (int m = 1; m < 64; m <<= 1) {
#pragma unroll
          for (int b = 0; b < 8; b++) pb[b] += __shfl_xor(pb[b], m, 64);
        }
        float myv = selLane8(pb);
        if (lane < 8) stC(&giU[lane * G3 + j], myv);
      }
      postSlotQ(&gflag[local * 16], (unsigned)(t + 1));
    }
    if (blk >= 128 && blk < 192 && t < TLEN - 1) {  // gh producers (with bias)
      pollOne(cnt_gru, (unsigned)(NB * (t + 1)));   // WAR: all blocks done reading gh(t)
      int local = blk - 128;
      for (int r2 = 0; r2 < 3; r2++) {
        int j = local * 24 + wave * 3 + r2;
        const float4* w4 = (const float4*)(w_hh + (size_t)j * HID + k0);
        float4 w0 = w4[0], w1 = w4[1];
        float pb[8];
#pragma unroll
        for (int b = 0; b < 8; b++) pb[b] = dot4(hf[b][0], w0) + dot4(hf[b][1], w1);
#pragma unroll
        for (int m = 1; m < 64; m <<= 1) {
#pragma unroll
          for (int b = 0; b < 8; b++) pb[b] += __shfl_xor(pb[b], m, 64);
        }
        float bh = b_hh[j];
#pragma unroll
        for (int b = 0; b < 8; b++) pb[b] += bh;
        float myv = selLane8(pb);
        if (lane < 8) stC(&gh[lane * G3 + j], myv);
      }
      postSlotQ(&hflag[local * 16], (unsigned)(t + 1));
    }
    // ---- x_t normalize + write (all blocks); latches inv for next GRU ----
    pollOne(cnt_e, (unsigned)(NB * (t + 1)));
    if (tid < 8) inv_lds[tid] = 1.0f / ldC(&rs_acc[t * 8 + tid]);
    __syncthreads();
    for (int i = tid; i < ROWS * 8; i += NT) {
      int b = i / ROWS, vl = i - b * ROWS;
      out[(size_t)b * ((size_t)TLEN * VOC) + (size_t)t * VOC + v0 + vl] =
          p_lds[vl * 8 + b] * inv_lds[b];
    }
  }
}

extern "C" void kernel_launch(void* const* d_in, const int* in_sizes, int n_in,
                              void* d_out, int out_size, void* d_ws, size_t ws_size,
                              hipStream_t stream) {
  const float* x = (const float*)d_in[0];
  const float* enc_w = (const float*)d_in[1];
  const float* enc_b = (const float*)d_in[2];
  const float* out_w = (const float*)d_in[3];
  const float* out_b = (const float*)d_in[4];
  const float* emb_out = (const float*)d_in[5];
  const float* emb_in = (const float*)d_in[6];
  const float* ph = (const float*)d_in[7];
  const float* w_ih = (const float*)d_in[8];
  const float* b_ih = (const float*)d_in[9];
  const float* w_hh = (const float*)d_in[10];
  const float* b_hh = (const float*)d_in[11];
  const float* gum = (const float*)d_in[12];
  float* out = (float*)d_out;
  float* ws = (float*)d_ws;

  InformedRnnSenderFixedLengthGS_48704929136907_kernel<<<dim3(NB), dim3(NT), 0, stream>>>(
      x, enc_w, enc_b, out_w, out_b, emb_out, emb_in, ph, w_ih, b_ih, w_hh, b_hh, gum,
      out, ws);
}

// Round 8
// 2716.795 us; speedup vs baseline: 2.6993x; 2.6655x over previous
//
#include <hip/hip_runtime.h>
#include <math.h>

constexpr int DIM = 2048, EMB = 512, HID = 512, VOC = 32000, TLEN = 32, G3 = 1536;
constexpr int NB = 256;     // blocks; 1 block/CU co-resident -- PROVEN topology
constexpr int NT = 256;     // threads/block (4 waves) -- PROVEN 256-VGPR codegen
constexpr int ROWS = 125;   // vocab rows per block
constexpr int GSTEP = 12288; // floats per gh/giU time slice ([8][1536])
constexpr unsigned MAGIC = 0x13579BDFu;

// ---- workspace layout (float units) ----
constexpr size_t W_H1  = 0;                            // [8][2048]
constexpr size_t W_H2  = W_H1 + 16384;                 // [8][2048]
constexpr size_t W_IMG = W_H2 + 16384;                 // [8][512]
constexpr size_t W_GI  = W_IMG + 4096;                 // [33][8][1536] giU time slices
constexpr size_t W_GH  = W_GI + 33 * (size_t)GSTEP;    // [33][8][1536] gh time slices
constexpr size_t W_SB  = W_GH + 33 * (size_t)GSTEP;    // [32][4096] per-step e accumulators
constexpr size_t W_RS  = W_SB + (size_t)TLEN * 4096;   // [32][8] per-step rowsum accumulators
constexpr size_t W_AF  = W_RS + TLEN * 8;              // 256 slots x 16 uints (encoder arrive)
constexpr size_t W_GF  = W_AF + 256 * 16;              // 64 slots (gi done)
constexpr size_t W_HF  = W_GF + 64 * 16;               // 64 slots (gh done)
constexpr size_t W_CNT = W_HF + 64 * 16;               // cnt_e (16 uints)
constexpr size_t W_RDY = W_CNT + 16;                   // 1 slot (init handshake)
constexpr int FLAG_WORDS = 256 * 16 + 64 * 16 * 2 + 16;  // zeroed region (excl. ready)

__device__ __forceinline__ float dot4(float4 a, float4 b) {
  return a.x * b.x + a.y * b.y + a.z * b.z + a.w * b.w;
}
__device__ __forceinline__ float4 fma4(float4 acc, float s, float4 v) {
  acc.x += s * v.x; acc.y += s * v.y; acc.z += s * v.z; acc.w += s * v.w; return acc;
}
__device__ __forceinline__ float4 add4(float4 a, float4 b) {
  a.x += b.x; a.y += b.y; a.z += b.z; a.w += b.w; return a;
}
__device__ __forceinline__ float sigm(float x) { return 1.0f / (1.0f + __expf(-x)); }
__device__ __forceinline__ float selLane8(const float pb[8]) {
  int lane = threadIdx.x & 63;
  float r = 0.0f;
#pragma unroll
  for (int b = 0; b < 8; b++) r = (lane == b) ? pb[b] : r;
  return r;
}

// ---- coherent (cache-bypassing) accessors for step-varying cross-block data ----
__device__ __forceinline__ void stC(float* p, float v) {
  __hip_atomic_store(p, v, __ATOMIC_RELAXED, __HIP_MEMORY_SCOPE_AGENT);
}
__device__ __forceinline__ float ldC(const float* p) {
  return __hip_atomic_load(p, __ATOMIC_RELAXED, __HIP_MEMORY_SCOPE_AGENT);
}
__device__ __forceinline__ void vdrain() {
  asm volatile("s_waitcnt vmcnt(0)" ::: "memory");
}

template <int KLEN>
__device__ __forceinline__ void rowdot8(const float* __restrict__ wrow,
                                        const float* __restrict__ xsrc, float pb[8]) {
  constexpr int PER = KLEN / 64;
  constexpr int NF4 = PER / 4;
  int lane = threadIdx.x & 63;
  int k0 = lane * PER;
  const float4* w4 = (const float4*)(wrow + k0);
  float4 wv[NF4];
#pragma unroll
  for (int i = 0; i < NF4; i++) wv[i] = w4[i];
#pragma unroll
  for (int b = 0; b < 8; b++) {
    const float4* x4 = (const float4*)(xsrc + b * KLEN + k0);
    float s = 0.0f;
#pragma unroll
    for (int i = 0; i < NF4; i++) s += dot4(x4[i], wv[i]);
    pb[b] = s;
  }
#pragma unroll
  for (int m = 1; m < 64; m <<= 1) {
#pragma unroll
    for (int b = 0; b < 8; b++) pb[b] += __shfl_xor(pb[b], m, 64);
  }
}

// ---- fenced protocol (init / encoder phases only) ----
__device__ __forceinline__ void postSlotF(unsigned* slot, unsigned val) {
  __syncthreads();
  if (threadIdx.x == 0) {
    __threadfence();
    __hip_atomic_store(slot, val, __ATOMIC_RELEASE, __HIP_MEMORY_SCOPE_AGENT);
  }
}
__device__ __forceinline__ void pollSlotsF(const unsigned* slots, int n, unsigned tgt) {
  int tid = threadIdx.x;
  if (tid < n) {
    const unsigned* p = slots + (size_t)tid * 16;
    while (__hip_atomic_load(p, __ATOMIC_RELAXED, __HIP_MEMORY_SCOPE_AGENT) < tgt)
      __builtin_amdgcn_s_sleep(1);
  }
  __syncthreads();
  __threadfence();
}

// ---- fence-free steady-state: coherent data + drained release ----
__device__ __forceinline__ void postSlotQ(unsigned* slot, unsigned val) {
  vdrain();
  __syncthreads();
  if (threadIdx.x == 0)
    __hip_atomic_store(slot, val, __ATOMIC_RELAXED, __HIP_MEMORY_SCOPE_AGENT);
}
__device__ __forceinline__ void pollOne(const unsigned* p, unsigned tgt) {
  if (threadIdx.x == 0) {
    while (__hip_atomic_load(p, __ATOMIC_RELAXED, __HIP_MEMORY_SCOPE_AGENT) < tgt)
      __builtin_amdgcn_s_sleep(1);
  }
  __syncthreads();
  asm volatile("" ::: "memory");   // compiler fence: no hoisting above the poll
}

// one vocab row: logits dot + butterfly + gumbel/exp + p store + e-accum
__device__ __forceinline__ void vocabRow(int r, float4 a0, float4 a1, float4 i0, float4 i1,
                                         const float4 hf[8][2], float4 ea[8][2],
                                         float sums[8], float* __restrict__ p_lds,
                                         const float* __restrict__ gum_lds) {
  int lane = threadIdx.x & 63;
  float pb[8];
#pragma unroll
  for (int b = 0; b < 8; b++) pb[b] = dot4(hf[b][0], a0) + dot4(hf[b][1], a1);
#pragma unroll
  for (int m = 1; m < 64; m <<= 1) {
#pragma unroll
    for (int b = 0; b < 8; b++) pb[b] += __shfl_xor(pb[b], m, 64);
  }
#pragma unroll
  for (int b = 0; b < 8; b++) {
    pb[b] = __expf(pb[b] + gum_lds[r * 8 + b]);
    sums[b] += pb[b];
  }
  if (lane == 0) {
    *(float4*)&p_lds[r * 8] = make_float4(pb[0], pb[1], pb[2], pb[3]);
    *(float4*)&p_lds[r * 8 + 4] = make_float4(pb[4], pb[5], pb[6], pb[7]);
  }
#pragma unroll
  for (int b = 0; b < 8; b++) {
    ea[b][0] = fma4(ea[b][0], pb[b], i0);
    ea[b][1] = fma4(ea[b][1], pb[b], i1);
  }
}

__global__ void __launch_bounds__(NT, 1)
InformedRnnSenderFixedLengthGS_48704929136907_kernel(
    const float* __restrict__ x, const float* __restrict__ enc_w,
    const float* __restrict__ enc_b, const float* __restrict__ out_w,
    const float* __restrict__ out_b, const float* __restrict__ emb_out,
    const float* __restrict__ emb_in, const float* __restrict__ ph,
    const float* __restrict__ w_ih, const float* __restrict__ b_ih,
    const float* __restrict__ w_hh, const float* __restrict__ b_hh,
    const float* __restrict__ gum, float* __restrict__ out, float* __restrict__ ws) {
  const int tid = threadIdx.x, blk = blockIdx.x;
  const int lane = tid & 63, wave = tid >> 6;

  float* h1 = ws + W_H1;
  float* h2 = ws + W_H2;
  float* img = ws + W_IMG;
  float* giU = ws + W_GI;     // slice t = giU + t*GSTEP
  float* gh = ws + W_GH;      // slice t = gh + t*GSTEP
  float* sbufU = ws + W_SB;
  float* rs_acc = ws + W_RS;
  unsigned* aflag = (unsigned*)(ws + W_AF);
  unsigned* gflag = (unsigned*)(ws + W_GF);
  unsigned* hflag = (unsigned*)(ws + W_HF);
  unsigned* cnt_e = (unsigned*)(ws + W_CNT);
  unsigned* ready = (unsigned*)(ws + W_RDY);

  __shared__ float h_lds[4096];      // [8][512] hidden state
  __shared__ float red_e[4096];      // cross-wave e reduce scratch
  __shared__ float p_lds[ROWS * 8];
  __shared__ float gum_lds[ROWS * 8];
  __shared__ float bih_lds[G3];
  __shared__ float red_rs[32];
  __shared__ float inv_lds[8];

  // ---- init handshake: block 0 zeroes flags, then releases MAGIC ----
  if (blk == 0) {
    for (int i = tid; i < FLAG_WORDS; i += NT) aflag[i] = 0u;
    __syncthreads();
    if (tid == 0) {
      __threadfence();
      __hip_atomic_store(ready, MAGIC, __ATOMIC_RELEASE, __HIP_MEMORY_SCOPE_AGENT);
    }
  }
  if (tid == 0) {
    while (__hip_atomic_load(ready, __ATOMIC_ACQUIRE, __HIP_MEMORY_SCOPE_AGENT) != MAGIC)
      __builtin_amdgcn_s_sleep(1);
  }
  __syncthreads();
  __threadfence();

  // ---- E1: h1 = tanh(x @ enc_w0^T + b0) ----
#pragma unroll
  for (int rr = 0; rr < 2; rr++) {
    int o = blk * 8 + wave * 2 + rr;
    float pb[8];
    rowdot8<2048>(enc_w + (size_t)o * DIM, x, pb);
    float eb = enc_b[o];
#pragma unroll
    for (int b = 0; b < 8; b++) pb[b] = tanhf(pb[b] + eb);
    float myv = selLane8(pb);
    if (lane < 8) h1[lane * DIM + o] = myv;
  }
  postSlotF(&aflag[blk * 16], 1u);
  pollSlotsF(aflag, 256, 1u);

  // ---- E2 ----
#pragma unroll
  for (int rr = 0; rr < 2; rr++) {
    int o = blk * 8 + wave * 2 + rr;
    float pb[8];
    rowdot8<2048>(enc_w + (size_t)DIM * DIM + (size_t)o * DIM, h1, pb);
    float eb = enc_b[DIM + o];
#pragma unroll
    for (int b = 0; b < 8; b++) pb[b] = tanhf(pb[b] + eb);
    float myv = selLane8(pb);
    if (lane < 8) h2[lane * DIM + o] = myv;
  }
  postSlotF(&aflag[blk * 16], 2u);
  pollSlotsF(aflag, 256, 2u);

  // ---- E3: img (blk<64), gh slice 0 with bias (64..127), giU slice 0 = 0 (128..191) ----
  if (blk < 64) {
#pragma unroll
    for (int rr = 0; rr < 2; rr++) {
      int o = blk * 8 + wave * 2 + rr;
      float pb[8];
      rowdot8<2048>(out_w + (size_t)o * DIM, h2, pb);
      float ob = out_b[o];
#pragma unroll
      for (int b = 0; b < 8; b++) pb[b] += ob;
      float myv = selLane8(pb);
      if (lane < 8) img[lane * EMB + o] = myv;
    }
  } else if (blk < 128) {
    int local = blk - 64;
    int kk = lane * 8;
    float4 p0 = *(const float4*)(ph + kk);
    float4 p1 = *(const float4*)(ph + kk + 4);
    for (int r = 0; r < 6; r++) {
      int j = local * 24 + wave * 6 + r;
      const float4* w4 = (const float4*)(w_hh + (size_t)j * HID + kk);
      float s = dot4(p0, w4[0]) + dot4(p1, w4[1]);
#pragma unroll
      for (int m = 1; m < 64; m <<= 1) s += __shfl_xor(s, m, 64);
      float val = s + b_hh[j];
      if (lane < 8) gh[lane * G3 + j] = val;   // slice 0
    }
  } else if (blk < 192) {
    int local = blk - 128;
    for (int r = 0; r < 6; r++) {
      int j = local * 24 + wave * 6 + r;
      if (lane < 8) giU[lane * G3 + j] = 0.0f;  // slice 0 (e0 == 0)
    }
  }
  for (int i = tid; i < 4096; i += NT) h_lds[i] = ph[i & 511];
  for (int i = tid; i < G3; i += NT) bih_lds[i] = b_ih[i];
  if (tid < 8) inv_lds[tid] = 1.0f;  // step-0 giU is zero, inv moot
  __syncthreads();
  postSlotF(&aflag[blk * 16], 3u);
  pollSlotsF(aflag, 256, 3u);

  const int v0 = blk * ROWS;
  const int k0 = lane * 8;
  const int rbeg = (wave * ROWS) / 4, rend = ((wave + 1) * ROWS) / 4;

  for (int t = 0; t < TLEN; ++t) {
    // 0) coalesced gumbel tile load (in flight during the gate wait)
    for (int i = tid; i < ROWS * 8; i += NT) {
      int b = i / ROWS, vl = i - b * ROWS;
      gum_lds[vl * 8 + b] = gum[(size_t)t * (8 * VOC) + (size_t)b * VOC + v0 + vl];
    }
    // 1) wait for this step's gates (64+64 slot poll, no cache fence)
    if (t > 0) {
      if (tid < 64) {
        const unsigned* p = gflag + (size_t)tid * 16;
        while (__hip_atomic_load(p, __ATOMIC_RELAXED, __HIP_MEMORY_SCOPE_AGENT) < (unsigned)t)
          __builtin_amdgcn_s_sleep(1);
      } else if (tid < 128) {
        const unsigned* p = hflag + (size_t)(tid - 64) * 16;
        while (__hip_atomic_load(p, __ATOMIC_RELAXED, __HIP_MEMORY_SCOPE_AGENT) < (unsigned)t)
          __builtin_amdgcn_s_sleep(1);
      }
      __syncthreads();
      asm volatile("" ::: "memory");
    }
    // 2) GRU elementwise update from time-slice t (bypassing loads, proven protocol)
    {
      const float* giT = giU + (size_t)t * GSTEP;
      const float* ghT = gh + (size_t)t * GSTEP;
#pragma unroll
      for (int qq = 0; qq < 4; qq++) {
        int i4 = tid + NT * qq;          // float4 index in [0,1024)
        int b = i4 >> 7, k = (i4 & 127) * 4;
        float invb = inv_lds[b];
        const float* gib = giT + b * G3 + k;
        const float* ghb = ghT + b * G3 + k;
        float4 iru, izu, inu, hrv, hzv, hnv;
        iru.x = ldC(gib + 0); iru.y = ldC(gib + 1); iru.z = ldC(gib + 2); iru.w = ldC(gib + 3);
        izu.x = ldC(gib + 512); izu.y = ldC(gib + 513); izu.z = ldC(gib + 514); izu.w = ldC(gib + 515);
        inu.x = ldC(gib + 1024); inu.y = ldC(gib + 1025); inu.z = ldC(gib + 1026); inu.w = ldC(gib + 1027);
        hrv.x = ldC(ghb + 0); hrv.y = ldC(ghb + 1); hrv.z = ldC(ghb + 2); hrv.w = ldC(ghb + 3);
        hzv.x = ldC(ghb + 512); hzv.y = ldC(ghb + 513); hzv.z = ldC(ghb + 514); hzv.w = ldC(ghb + 515);
        hnv.x = ldC(ghb + 1024); hnv.y = ldC(ghb + 1025); hnv.z = ldC(ghb + 1026); hnv.w = ldC(ghb + 1027);
        float4 br = *(const float4*)&bih_lds[k];
        float4 bz = *(const float4*)&bih_lds[512 + k];
        float4 bn = *(const float4*)&bih_lds[1024 + k];
        float4 hp = *(const float4*)&h_lds[b * 512 + k];
        float4 hv;
        {
          float r0 = sigm(invb * iru.x + br.x + hrv.x), z0 = sigm(invb * izu.x + bz.x + hzv.x);
          float n0 = tanhf(invb * inu.x + bn.x + r0 * hnv.x);
          hv.x = (1.0f - z0) * n0 + z0 * hp.x;
          r0 = sigm(invb * iru.y + br.y + hrv.y); z0 = sigm(invb * izu.y + bz.y + hzv.y);
          n0 = tanhf(invb * inu.y + bn.y + r0 * hnv.y);
          hv.y = (1.0f - z0) * n0 + z0 * hp.y;
          r0 = sigm(invb * iru.z + br.z + hrv.z); z0 = sigm(invb * izu.z + bz.z + hzv.z);
          n0 = tanhf(invb * inu.z + bn.z + r0 * hnv.z);
          hv.z = (1.0f - z0) * n0 + z0 * hp.z;
          r0 = sigm(invb * iru.w + br.w + hrv.w); z0 = sigm(invb * izu.w + bz.w + hzv.w);
          n0 = tanhf(invb * inu.w + bn.w + r0 * hnv.w);
          hv.w = (1.0f - z0) * n0 + z0 * hp.w;
        }
        *(float4*)&h_lds[b * 512 + k] = hv;
      }
    }
    __syncthreads();
    // 3) per-lane h fragments
    float4 hf[8][2];
#pragma unroll
    for (int b = 0; b < 8; b++) {
      hf[b][0] = *(const float4*)(h_lds + b * 512 + k0);
      hf[b][1] = *(const float4*)(h_lds + b * 512 + k0 + 4);
    }
    // 4) vocab rows, batched by 8 with hoisted loads
    float4 ea[8][2];
#pragma unroll
    for (int b = 0; b < 8; b++) { ea[b][0] = make_float4(0, 0, 0, 0); ea[b][1] = make_float4(0, 0, 0, 0); }
    float sums[8] = {0, 0, 0, 0, 0, 0, 0, 0};
    int r = rbeg;
    for (; r + 8 <= rend; r += 8) {
      float4 A0[8], A1[8], I0[8], I1[8];
#pragma unroll
      for (int u = 0; u < 8; u++) {
        int v = v0 + r + u;
        const float4* wo = (const float4*)(emb_out + (size_t)v * EMB + k0);
        A0[u] = wo[0]; A1[u] = wo[1];
        const float4* wi = (const float4*)(emb_in + (size_t)v * EMB + k0);
        I0[u] = wi[0]; I1[u] = wi[1];
      }
#pragma unroll
      for (int u = 0; u < 8; u++)
        vocabRow(r + u, A0[u], A1[u], I0[u], I1[u], hf, ea, sums, p_lds, gum_lds);
    }
    {
      int rem = rend - r;
      if (rem > 0) {
        float4 A0[8], A1[8], I0[8], I1[8];
#pragma unroll
        for (int u = 0; u < 8; u++) {
          int rr = (u < rem) ? (r + u) : r;
          int v = v0 + rr;
          const float4* wo = (const float4*)(emb_out + (size_t)v * EMB + k0);
          A0[u] = wo[0]; A1[u] = wo[1];
          const float4* wi = (const float4*)(emb_in + (size_t)v * EMB + k0);
          I0[u] = wi[0]; I1[u] = wi[1];
        }
#pragma unroll
        for (int u = 0; u < 8; u++)
          if (u < rem)
            vocabRow(r + u, A0[u], A1[u], I0[u], I1[u], hf, ea, sums, p_lds, gum_lds);
      }
    }
    // 5) cross-wave e reduce into red_e, rowsums into red_rs
    for (int w = 0; w < 4; w++) {
      if (wave == w) {
#pragma unroll
        for (int b = 0; b < 8; b++) {
          float4* d = (float4*)&red_e[b * 512 + k0];
          if (w == 0) { d[0] = ea[b][0]; d[1] = ea[b][1]; }
          else { d[0] = add4(d[0], ea[b][0]); d[1] = add4(d[1], ea[b][1]); }
        }
      }
      __syncthreads();
    }
    if (lane == 0) {
      *(float4*)&red_rs[wave * 8] = make_float4(sums[0], sums[1], sums[2], sums[3]);
      *(float4*)&red_rs[wave * 8 + 4] = make_float4(sums[4], sums[5], sums[6], sums[7]);
    }
    __syncthreads();
    // 6) hardware-atomic e + rowsum reduction into this step's slot
    {
      float* sb = sbufU + (size_t)t * 4096;
      for (int i = tid; i < 4096; i += NT) unsafeAtomicAdd(&sb[i], red_e[i]);
      if (tid < 8) {
        float tot = red_rs[tid] + red_rs[8 + tid] + red_rs[16 + tid] + red_rs[24 + tid];
        unsafeAtomicAdd(&rs_acc[t * 8 + tid], tot);
      }
    }
    vdrain();           // atomics acked at coherence point
    __syncthreads();
    if (tid == 0)
      __hip_atomic_fetch_add(cnt_e, 1u, __ATOMIC_RELAXED, __HIP_MEMORY_SCOPE_AGENT);

    // ---- roles (gh has NO wait: time-sliced buffers removed the WAR/barrier) ----
    if (blk >= 128 && blk < 192 && t < TLEN - 1) {  // gh producers (with bias)
      float* ghN = gh + (size_t)(t + 1) * GSTEP;
      int local = blk - 128;
      for (int r2 = 0; r2 < 6; r2++) {
        int j = local * 24 + wave * 6 + r2;
        const float4* w4 = (const float4*)(w_hh + (size_t)j * HID + k0);
        float4 w0 = w4[0], w1 = w4[1];
        float pb[8];
#pragma unroll
        for (int b = 0; b < 8; b++) pb[b] = dot4(hf[b][0], w0) + dot4(hf[b][1], w1);
#pragma unroll
        for (int m = 1; m < 64; m <<= 1) {
#pragma unroll
          for (int b = 0; b < 8; b++) pb[b] += __shfl_xor(pb[b], m, 64);
        }
        float bh = b_hh[j];
#pragma unroll
        for (int b = 0; b < 8; b++) pb[b] += bh;
        float myv = selLane8(pb);
        if (lane < 8) stC(&ghN[lane * G3 + j], myv);
      }
      postSlotQ(&hflag[local * 16], (unsigned)(t + 1));
    }
    if (blk >= 64 && blk < 128 && t < TLEN - 1) {  // giU producers (need full e-sum)
      pollOne(cnt_e, (unsigned)(NB * (t + 1)));
      float sf[8][8];
#pragma unroll
      for (int b = 0; b < 8; b++)
#pragma unroll
        for (int q = 0; q < 8; q++)
          sf[b][q] = ldC(sbufU + (size_t)t * 4096 + b * 512 + k0 + q) * img[b * 512 + k0 + q];
      float* giN = giU + (size_t)(t + 1) * GSTEP;
      int local = blk - 64;
      for (int r2 = 0; r2 < 6; r2++) {
        int j = local * 24 + wave * 6 + r2;
        const float* wr = w_ih + (size_t)j * HID + k0;
        float4 w0 = *(const float4*)wr, w1 = *(const float4*)(wr + 4);
        float wv[8] = {w0.x, w0.y, w0.z, w0.w, w1.x, w1.y, w1.z, w1.w};
        float pb[8];
#pragma unroll
        for (int b = 0; b < 8; b++) {
          float s = 0.0f;
#pragma unroll
          for (int q = 0; q < 8; q++) s += sf[b][q] * wv[q];
          pb[b] = s;
        }
#pragma unroll
        for (int m = 1; m < 64; m <<= 1) {
#pragma unroll
          for (int b = 0; b < 8; b++) pb[b] += __shfl_xor(pb[b], m, 64);
        }
        float myv = selLane8(pb);
        if (lane < 8) stC(&giN[lane * G3 + j], myv);
      }
      postSlotQ(&gflag[local * 16], (unsigned)(t + 1));
    }
    // ---- x_t normalize + write (all blocks); latches inv for next GRU ----
    pollOne(cnt_e, (unsigned)(NB * (t + 1)));
    if (tid < 8) inv_lds[tid] = 1.0f / ldC(&rs_acc[t * 8 + tid]);
    __syncthreads();
    for (int i = tid; i < ROWS * 8; i += NT) {
      int b = i / ROWS, vl = i - b * ROWS;
      out[(size_t)b * ((size_t)TLEN * VOC) + (size_t)t * VOC + v0 + vl] =
          p_lds[vl * 8 + b] * inv_lds[b];
    }
  }
}

extern "C" void kernel_launch(void* const* d_in, const int* in_sizes, int n_in,
                              void* d_out, int out_size, void* d_ws, size_t ws_size,
                              hipStream_t stream) {
  const float* x = (const float*)d_in[0];
  const float* enc_w = (const float*)d_in[1];
  const float* enc_b = (const float*)d_in[2];
  const float* out_w = (const float*)d_in[3];
  const float* out_b = (const float*)d_in[4];
  const float* emb_out = (const float*)d_in[5];
  const float* emb_in = (const float*)d_in[6];
  const float* ph = (const float*)d_in[7];
  const float* w_ih = (const float*)d_in[8];
  const float* b_ih = (const float*)d_in[9];
  const float* w_hh = (const float*)d_in[10];
  const float* b_hh = (const float*)d_in[11];
  const float* gum = (const float*)d_in[12];
  float* out = (float*)d_out;
  float* ws = (float*)d_ws;

  InformedRnnSenderFixedLengthGS_48704929136907_kernel<<<dim3(NB), dim3(NT), 0, stream>>>(
      x, enc_w, enc_b, out_w, out_b, emb_out, emb_in, ph, w_ih, b_ih, w_hh, b_hh, gum,
      out, ws);
}